// Round 2
// 2480.239 us; speedup vs baseline: 1.4308x; 1.4308x over previous
//
#include <hip/hip_runtime.h>
#include <hip/hip_bf16.h>

// CYK forward. p-chain fp32; f-chain GEMM bf16x3 MFMA.
// Round 9: uv factorization (concat(lf,rf)@Wm = lf@Wm_top + rf@Wm_bot,
// u/v hoisted to once per chart cell) + TRIANGULAR diagonal-major packing
// of all per-cell arrays (chart_p/chart_v/cfh/cfl/uv) so the fixed
// workspace footprint is ~314 MB (round-8's rectangular uv needed 543 MB
// and overflowed the workspace -> memory fault).
// Packed cell index: dBase(d) + b*(L-d) + i.

typedef __attribute__((ext_vector_type(8))) short short8;
typedef __attribute__((ext_vector_type(4))) float f32x4;

constexpr int cB = 64, cL = 32, cNT = 64, cS = 128, cV = 50000;
constexpr int cEMB = 512, cSD = 512, cKQ = 4096; // quadrant k
constexpr int DMAX = 31, KS = 32;                // k-slice = 128
constexpr float cEPS = 1e-9f;
constexpr long TRIC = (long)cB * (cL * (cL + 1) / 2); // 33792 packed cells

__device__ __forceinline__ long dBase(int d) {
  return (long)cB * ((long)d * cL - ((long)d * (d - 1)) / 2);
}

__device__ __forceinline__ void split_bf16(float x, __hip_bfloat16& h, __hip_bfloat16& l) {
  h = __float2bfloat16(x);
  l = __float2bfloat16(x - __bfloat162float(h));
}

// ---------------- G quadrant permutes + Gsum2T ----------------
__global__ __launch_bounds__(256) void k_prep_g(const float* __restrict__ G,
                                                float* __restrict__ Gll,
                                                float* __restrict__ Ghh,
                                                float* __restrict__ GsumT) {
  int idx = blockIdx.x * 256 + threadIdx.x; // s*128+t
  int s = idx >> 7, t = idx & 127;
  bool lo = (s < 64) && (t < 64);
  bool hi = (s >= 64) && (t >= 64);
  int pl = s * 64 + t;                  // valid when lo
  int ph = (s - 64) * 64 + (t - 64);    // valid when hi
  float accum = 0.f;
  for (int a = 0; a < cNT; ++a) {
    float g = G[(size_t)a * 16384 + idx];
    accum += g;
    if (lo) Gll[(size_t)pl * cNT + a] = g;
    if (hi) Ghh[(size_t)ph * cNT + a] = g;
  }
  GsumT[t * cS + s] = accum;
}

// ---------------- WmT hi/lo split, layout [nn<1024][k<512] ----------------
// nn < 512: u half -> Wm[k][nn];  nn >= 512: v half -> Wm[512+k][nn-512].
__global__ __launch_bounds__(256) void k_prep_wmt(const float* __restrict__ Wm,
                                                  __hip_bfloat16* __restrict__ WmTh,
                                                  __hip_bfloat16* __restrict__ WmTl) {
  int idx = blockIdx.x * 256 + threadIdx.x; // nn*512 + k
  int k = idx & 511, nn = idx >> 9;
  int krow = k + ((nn >= 512) ? 512 : 0);
  float v = Wm[(size_t)krow * cSD + (nn & 511)];
  __hip_bfloat16 h, l;
  split_bf16(v, h, l);
  WmTh[idx] = h;
  WmTl[idx] = l;
}

// ---------------- diagonal 0 of chart_p + chart_v ----------------
__global__ void k_diag(const int* __restrict__ word,
                       const float* __restrict__ preterm,
                       const float* __restrict__ GsumT,
                       float* __restrict__ chart_p,
                       float* __restrict__ chart_v) {
  __shared__ float ps[128];
  int row = blockIdx.x;  // packed diag-0 cell = b*L + pos
  int tid = threadIdx.x; // 0..127
  int w = word[row];
  float val = (tid >= 64) ? preterm[(size_t)(tid - 64) * cV + w] : 0.f;
  float sum = val;
  #pragma unroll
  for (int off = 1; off < 64; off <<= 1) sum += __shfl_xor(sum, off, 64);
  float p_ = (tid >= 64) ? val / (sum + cEPS) : 0.f;
  size_t base = (size_t)row * cS;
  chart_p[base + tid] = p_;
  ps[tid] = p_;
  __syncthreads();
  float v = 0.f;
  for (int t = 64; t < 128; ++t) v = fmaf(GsumT[t * cS + tid], ps[t], v);
  chart_v[base + tid] = v;
}

// ---------------- fp32 GEMM micro ----------------
__device__ __forceinline__ void micro16(const float (*As)[68], const float (*Bs)[68],
                                        int r0, int c0, float acc[4][4]) {
  #pragma unroll
  for (int k = 0; k < 16; ++k) {
    float4 a4 = *(const float4*)&As[k][r0];
    float4 b4 = *(const float4*)&Bs[k][c0];
    float ar[4] = {a4.x, a4.y, a4.z, a4.w};
    float br[4] = {b4.x, b4.y, b4.z, b4.w};
    #pragma unroll
    for (int i = 0; i < 4; ++i)
      #pragma unroll
      for (int j = 0; j < 4; ++j)
        acc[i][j] = fmaf(ar[i], br[j], acc[i][j]);
  }
}

// ---------------- e table: e[cell][a][t_lo] = sum_s p_hi[s] G[a][64+s][t] ----------------
__global__ __launch_bounds__(256) void k_prep_e(const float* __restrict__ chart_p,
                                                const float* __restrict__ G,
                                                float* __restrict__ e_arr) {
  __shared__ float As[16][68];
  __shared__ float Bs[16][68];
  int tid = threadIdx.x;
  int rowTile = blockIdx.x * 64;
  int n0 = blockIdx.y * 64; // c-range = one a, t in [0,64)
  int a = n0 >> 6;
  int lr = tid >> 2, lk = (tid & 3) << 2;
  int bk = tid >> 4, bn = (tid & 15) << 2;
  int r0 = (tid >> 4) << 2, c0 = (tid & 15) << 2;
  float acc[4][4] = {};
  for (int kb = 0; kb < 64; kb += 16) {
    float4 av = *(const float4*)(chart_p + (size_t)(rowTile + lr) * cS + 64 + kb + lk);
    float4 bv = *(const float4*)(G + (size_t)a * 16384 + (size_t)(64 + kb + bk) * 128 + bn);
    __syncthreads();
    As[lk + 0][lr] = av.x; As[lk + 1][lr] = av.y;
    As[lk + 2][lr] = av.z; As[lk + 3][lr] = av.w;
    *(float4*)&Bs[bk][bn] = bv;
    __syncthreads();
    micro16(As, Bs, r0, c0, acc);
  }
  #pragma unroll
  for (int i = 0; i < 4; ++i) {
    float4 o = {acc[i][0], acc[i][1], acc[i][2], acc[i][3]};
    *(float4*)&e_arr[(size_t)(rowTile + r0 + i) * 4096 + n0 + c0] = o;
  }
}

// ---------------- f table: f[cell][a][s_lo] = sum_t G[a][s][64+t] p_hi[t] ----------------
// 8 cells per block; output range split over grid.y for occupancy.
__global__ __launch_bounds__(256) void k_prep_f(const float* __restrict__ chart_p,
                                                const float* __restrict__ G,
                                                float* __restrict__ f_arr) {
  __shared__ float ph[8][64];
  int tid = threadIdx.x;
  int cell0 = blockIdx.x * 8;
  for (int v = tid; v < 512; v += 256) {
    int cc = v >> 6, t = v & 63;
    ph[cc][t] = chart_p[(size_t)(cell0 + cc) * cS + 64 + t];
  }
  __syncthreads();
  int oo0 = blockIdx.y * 4;
  for (int oo = oo0; oo < oo0 + 4; ++oo) {
    int out_id = oo * 256 + tid; // a*64 + s
    int a = out_id >> 6, s = out_id & 63;
    const float* gb = G + (size_t)a * 16384 + (size_t)s * 128 + 64;
    float acc[8] = {};
    #pragma unroll 4
    for (int ch = 0; ch < 16; ++ch) {
      float4 g4 = *(const float4*)(gb + ch * 4);
      #pragma unroll
      for (int cc = 0; cc < 8; ++cc) {
        float4 p4 = *(const float4*)&ph[cc][ch * 4];
        acc[cc] = fmaf(g4.x, p4.x, acc[cc]);
        acc[cc] = fmaf(g4.y, p4.y, acc[cc]);
        acc[cc] = fmaf(g4.z, p4.z, acc[cc]);
        acc[cc] = fmaf(g4.w, p4.w, acc[cc]);
      }
    }
    #pragma unroll
    for (int cc = 0; cc < 8; ++cc)
      f_arr[(size_t)(cell0 + cc) * 4096 + out_id] = acc[cc];
  }
}

// ---------------- feat0 -> hi/lo planes (diag-0 cells) ----------------
__global__ __launch_bounds__(256) void k_feat0(const int* __restrict__ word,
                                               const float* __restrict__ WE,
                                               const float* __restrict__ Wp,
                                               const float* __restrict__ bp,
                                               __hip_bfloat16* __restrict__ cfh,
                                               __hip_bfloat16* __restrict__ cfl) {
  __shared__ float As[16][68];
  __shared__ float Bs[16][68];
  int tid = threadIdx.x;
  int rowTile = blockIdx.x * 64;
  int n0 = blockIdx.y * 64;
  int lr = tid >> 2, lk = (tid & 3) << 2;
  int bk = tid >> 4, bn = (tid & 15) << 2;
  int r0 = (tid >> 4) << 2, c0 = (tid & 15) << 2;
  const float* ap = WE + (size_t)word[rowTile + lr] * cEMB;
  float acc[4][4] = {};
  for (int kb = 0; kb < cEMB; kb += 16) {
    float4 av = *(const float4*)(ap + kb + lk);
    float4 bv = *(const float4*)(Wp + (size_t)(kb + bk) * cSD + n0 + bn);
    __syncthreads();
    As[lk + 0][lr] = av.x; As[lk + 1][lr] = av.y;
    As[lk + 2][lr] = av.z; As[lk + 3][lr] = av.w;
    *(float4*)&Bs[bk][bn] = bv;
    __syncthreads();
    micro16(As, Bs, r0, c0, acc);
  }
  float4 bpv = *(const float4*)(bp + n0 + c0);
  float bpr[4] = {bpv.x, bpv.y, bpv.z, bpv.w};
  #pragma unroll
  for (int i = 0; i < 4; ++i) {
    int row = rowTile + r0 + i; // packed diag-0 cell index
    size_t base = (size_t)row * cSD + n0 + c0;
    #pragma unroll
    for (int e = 0; e < 4; ++e) {
      float v = fmaxf(acc[i][e] + bpr[e], 0.f);
      __hip_bfloat16 h, l;
      split_bf16(v, h, l);
      cfh[base + e] = h;
      cfl[base + e] = l;
    }
  }
}

// ---------------- uv GEMM bf16x3 MFMA: cells of one diagonal -> [u|v] ----------------
// A = chart_f rows (K=512), B = WmT2 (1024 x 512), C = uv[cell][1024] fp32.
// Packed cell index = cellBase + GEMM row (no div/mod).
__global__ __launch_bounds__(256) void k_uv_mfma(
    const __hip_bfloat16* __restrict__ cfh, const __hip_bfloat16* __restrict__ cfl,
    const __hip_bfloat16* __restrict__ WmTh, const __hip_bfloat16* __restrict__ WmTl,
    float* __restrict__ uv, long cellBase, int M) {
  __shared__ short Ash[2 * 128 * 40];
  __shared__ short Bsh[2 * 128 * 40];
  int tid = threadIdx.x;
  int rowTile = blockIdx.y * 128;
  int colTile = blockIdx.x * 128;
  int m0 = tid >> 2, kq8 = (tid & 3) * 8;

  long offA[2];
  #pragma unroll
  for (int h = 0; h < 2; ++h) {
    int row = rowTile + m0 + h * 64;
    if (row >= M) row = M - 1;
    offA[h] = (cellBase + row) * cSD;
  }
  long offB0 = (long)(colTile + m0) * 512;
  long offB1 = (long)(colTile + m0 + 64) * 512;

  f32x4 acc[4][4];
  f32x4 zero = {0.f, 0.f, 0.f, 0.f};
  #pragma unroll
  for (int a_ = 0; a_ < 4; ++a_)
    #pragma unroll
    for (int b_ = 0; b_ < 4; ++b_) acc[a_][b_] = zero;

  int lane = tid & 63, wid = tid >> 6;
  int wm = wid >> 1, wn = wid & 1;
  int fr = lane & 15, fq = lane >> 4;

  int4 pA0h = *(const int4*)(const void*)(cfh + offA[0] + kq8);
  int4 pA1h = *(const int4*)(const void*)(cfh + offA[1] + kq8);
  int4 pA0l = *(const int4*)(const void*)(cfl + offA[0] + kq8);
  int4 pA1l = *(const int4*)(const void*)(cfl + offA[1] + kq8);
  int4 pB0h = *(const int4*)(const void*)(WmTh + offB0 + kq8);
  int4 pB1h = *(const int4*)(const void*)(WmTh + offB1 + kq8);
  int4 pB0l = *(const int4*)(const void*)(WmTl + offB0 + kq8);
  int4 pB1l = *(const int4*)(const void*)(WmTl + offB1 + kq8);

  for (int kb = 0; kb < 512; kb += 32) {
    __syncthreads();
    *(int4*)&Ash[(0 * 128 + m0) * 40 + kq8] = pA0h;
    *(int4*)&Ash[(0 * 128 + m0 + 64) * 40 + kq8] = pA1h;
    *(int4*)&Ash[(1 * 128 + m0) * 40 + kq8] = pA0l;
    *(int4*)&Ash[(1 * 128 + m0 + 64) * 40 + kq8] = pA1l;
    *(int4*)&Bsh[(0 * 128 + m0) * 40 + kq8] = pB0h;
    *(int4*)&Bsh[(0 * 128 + m0 + 64) * 40 + kq8] = pB1h;
    *(int4*)&Bsh[(1 * 128 + m0) * 40 + kq8] = pB0l;
    *(int4*)&Bsh[(1 * 128 + m0 + 64) * 40 + kq8] = pB1l;
    __syncthreads();
    int kn = kb + 32;
    if (kn < 512) {
      pA0h = *(const int4*)(const void*)(cfh + offA[0] + kn + kq8);
      pA1h = *(const int4*)(const void*)(cfh + offA[1] + kn + kq8);
      pA0l = *(const int4*)(const void*)(cfl + offA[0] + kn + kq8);
      pA1l = *(const int4*)(const void*)(cfl + offA[1] + kn + kq8);
      pB0h = *(const int4*)(const void*)(WmTh + offB0 + kn + kq8);
      pB1h = *(const int4*)(const void*)(WmTh + offB1 + kn + kq8);
      pB0l = *(const int4*)(const void*)(WmTl + offB0 + kn + kq8);
      pB1l = *(const int4*)(const void*)(WmTl + offB1 + kn + kq8);
    }
    short8 af[2][4], bf[2][4];
    #pragma unroll
    for (int pl = 0; pl < 2; ++pl)
      #pragma unroll
      for (int mf = 0; mf < 4; ++mf)
        af[pl][mf] = *(const short8*)&Ash[(pl * 128 + wm * 64 + mf * 16 + fr) * 40 + fq * 8];
    #pragma unroll
    for (int pl = 0; pl < 2; ++pl)
      #pragma unroll
      for (int nf = 0; nf < 4; ++nf)
        bf[pl][nf] = *(const short8*)&Bsh[(pl * 128 + wn * 64 + nf * 16 + fr) * 40 + fq * 8];
    #pragma unroll
    for (int mf = 0; mf < 4; ++mf)
      #pragma unroll
      for (int nf = 0; nf < 4; ++nf) {
        acc[mf][nf] = __builtin_amdgcn_mfma_f32_16x16x32_bf16(af[0][mf], bf[0][nf], acc[mf][nf], 0, 0, 0);
        acc[mf][nf] = __builtin_amdgcn_mfma_f32_16x16x32_bf16(af[0][mf], bf[1][nf], acc[mf][nf], 0, 0, 0);
        acc[mf][nf] = __builtin_amdgcn_mfma_f32_16x16x32_bf16(af[1][mf], bf[0][nf], acc[mf][nf], 0, 0, 0);
      }
  }
  #pragma unroll
  for (int mf = 0; mf < 4; ++mf)
    #pragma unroll
    for (int r = 0; r < 4; ++r) {
      int row = rowTile + wm * 64 + mf * 16 + fq * 4 + r;
      if (row >= M) continue;
      float* op = uv + (cellBase + row) * 1024 + colTile + wn * 64;
      #pragma unroll
      for (int nf = 0; nf < 4; ++nf)
        op[nf * 16 + fr] = acc[mf][nf][r];
    }
}

// ---------------- quadrant outer-product: O[row][4096] over d-range ----------------
__global__ __launch_bounds__(256) void k_outer(const float* __restrict__ chart_p,
                                               float* __restrict__ O,
                                               int ln, int n, int chunkStart,
                                               int dlo, int dhi, int soff, int toff) {
  __shared__ float lp[DMAX][64];
  __shared__ float rp[DMAX][64];
  int tid = threadIdx.x;
  int row = chunkStart + blockIdx.x;
  int b = row / n, i = row - b * n;
  if (tid < 128) {
    int lane = tid & 63;
    for (int dd = dlo + (tid >> 6); dd <= dhi; dd += 2) {
      long lc = dBase(dd) + (long)b * (cL - dd) + i;
      lp[dd - dlo][lane] = chart_p[lc * cS + soff + lane];
    }
  } else {
    int t2 = tid - 128;
    int lane = t2 & 63;
    for (int dd = dlo + (t2 >> 6); dd <= dhi; dd += 2) {
      int dr = ln - dd - 2;
      long rc = dBase(dr) + (long)b * (cL - dr) + (i + dd + 1);
      rp[dd - dlo][lane] = chart_p[rc * cS + toff + lane];
    }
  }
  __syncthreads();
  float acc[16];
  #pragma unroll
  for (int j = 0; j < 16; ++j) acc[j] = 0.f;
  int s = tid >> 2, t0 = (tid & 3) << 4;
  int dcount = dhi - dlo + 1;
  for (int dd = 0; dd < dcount; ++dd) {
    float lps = lp[dd][s];
    #pragma unroll
    for (int qq = 0; qq < 4; ++qq) {
      float4 r4 = *(const float4*)&rp[dd][t0 + qq * 4];
      acc[qq * 4 + 0] = fmaf(lps, r4.x, acc[qq * 4 + 0]);
      acc[qq * 4 + 1] = fmaf(lps, r4.y, acc[qq * 4 + 1]);
      acc[qq * 4 + 2] = fmaf(lps, r4.z, acc[qq * 4 + 2]);
      acc[qq * 4 + 3] = fmaf(lps, r4.w, acc[qq * 4 + 3]);
    }
  }
  float* op = O + (size_t)blockIdx.x * cKQ + (size_t)tid * 16; // p = s*64+t
  #pragma unroll
  for (int j = 0; j < 4; ++j) {
    float4 o = {acc[j * 4 + 0], acc[j * 4 + 1], acc[j * 4 + 2], acc[j * 4 + 3]};
    *(float4*)&op[j * 4] = o;
  }
}

// ---------------- scores GEMM: O(CHx4096) @ Gq(4096x64), K-split 32 ----------------
__global__ __launch_bounds__(256) void k_scores(const float* __restrict__ O,
                                                const float* __restrict__ Gq,
                                                float* __restrict__ scoresP,
                                                int CHpad, int rows) {
  __shared__ float As[32][128];
  __shared__ float Bs[32][64];
  int tid = threadIdx.x;
  int rowTile = blockIdx.x * 128;
  int ks = blockIdx.y;       // 0..31
  int kstart = ks * 128;
  int sm = tid & 127, skq = (tid >> 7) * 16;
  int bq = tid >> 4, bn4 = (tid & 15) * 4;
  int m0 = (tid & 15) << 2, n0 = (tid >> 4) << 2;
  const float* ap = O + (size_t)(rowTile + sm) * cKQ + kstart + skq;
  float acc[8][4] = {};
  for (int kb = 0; kb < 128; kb += 32) {
    float4 a0 = *(const float4*)(ap + kb + 0);
    float4 a1 = *(const float4*)(ap + kb + 4);
    float4 a2 = *(const float4*)(ap + kb + 8);
    float4 a3 = *(const float4*)(ap + kb + 12);
    float4 b0 = *(const float4*)(Gq + (size_t)(kstart + kb + bq * 2) * cNT + bn4);
    float4 b1 = *(const float4*)(Gq + (size_t)(kstart + kb + bq * 2 + 1) * cNT + bn4);
    __syncthreads();
    As[skq + 0][sm] = a0.x; As[skq + 1][sm] = a0.y; As[skq + 2][sm] = a0.z; As[skq + 3][sm] = a0.w;
    As[skq + 4][sm] = a1.x; As[skq + 5][sm] = a1.y; As[skq + 6][sm] = a1.z; As[skq + 7][sm] = a1.w;
    As[skq + 8][sm] = a2.x; As[skq + 9][sm] = a2.y; As[skq + 10][sm] = a2.z; As[skq + 11][sm] = a2.w;
    As[skq + 12][sm] = a3.x; As[skq + 13][sm] = a3.y; As[skq + 14][sm] = a3.z; As[skq + 15][sm] = a3.w;
    *(float4*)&Bs[bq * 2][bn4] = b0;
    *(float4*)&Bs[bq * 2 + 1][bn4] = b1;
    __syncthreads();
    #pragma unroll
    for (int k = 0; k < 32; ++k) {
      float4 av0 = *(const float4*)&As[k][m0];
      float4 av1 = *(const float4*)&As[k][m0 + 64];
      float4 bv = *(const float4*)&Bs[k][n0];
      float ar[8] = {av0.x, av0.y, av0.z, av0.w, av1.x, av1.y, av1.z, av1.w};
      float br[4] = {bv.x, bv.y, bv.z, bv.w};
      #pragma unroll
      for (int i = 0; i < 8; ++i)
        #pragma unroll
        for (int j = 0; j < 4; ++j)
          acc[i][j] = fmaf(ar[i], br[j], acc[i][j]);
    }
  }
  #pragma unroll
  for (int i = 0; i < 8; ++i) {
    int row = rowTile + m0 + (i >> 2) * 64 + (i & 3);
    if (row < rows) {
      float4 o = {acc[i][0], acc[i][1], acc[i][2], acc[i][3]};
      *(float4*)&scoresP[((size_t)ks * CHpad + row) * cNT + n0] = o;
    }
  }
}

// ---------------- partial-reduce + e/f corrections + normalize + chart_v ----------------
__global__ void k_normp(const float* __restrict__ scoresP,
                        const float* __restrict__ e_arr,
                        const float* __restrict__ f_arr,
                        const float* __restrict__ GsumT,
                        float* __restrict__ chart_p,
                        float* __restrict__ chart_v,
                        int ln, int nn, int CHpad, int chunkStart,
                        int useGemm, int useEF) {
  __shared__ float sP[128]; // [0:64) rp_lo, [64:128) lp_lo
  __shared__ float ps[64];
  int lr = blockIdx.x;
  int tid = threadIdx.x; // 0..127
  int row = chunkStart + lr;
  int b = row / nn, i = row - b * nn;
  if (useEF) {
    long c2 = dBase(ln - 2) + (long)b * (nn + 1); // width at diag ln-2 is nn+1
    if (tid < 64)
      sP[tid] = chart_p[(c2 + i + 1) * cS + tid];
    else
      sP[tid] = chart_p[(c2 + i) * cS + (tid - 64)];
    __syncthreads();
  }
  float val = 0.f;
  if (tid < 64) {
    if (useGemm)
      for (int ks = 0; ks < KS; ++ks)
        val += scoresP[((size_t)ks * CHpad + lr) * cNT + tid];
    if (useEF) {
      const float4* e4 = (const float4*)&e_arr[((size_t)(b * cL + i) * 4096) + tid * 64];
      const float4* f4 = (const float4*)&f_arr[((size_t)(b * cL + i + ln - 1) * 4096) + tid * 64];
      float ce = 0.f, cf = 0.f;
      #pragma unroll 4
      for (int q = 0; q < 16; ++q) {
        float4 ev = e4[q];
        float4 fv = f4[q];
        float4 rv = *(const float4*)&sP[q * 4];
        float4 lv = *(const float4*)&sP[64 + q * 4];
        ce = fmaf(ev.x, rv.x, ce); ce = fmaf(ev.y, rv.y, ce);
        ce = fmaf(ev.z, rv.z, ce); ce = fmaf(ev.w, rv.w, ce);
        cf = fmaf(fv.x, lv.x, cf); cf = fmaf(fv.y, lv.y, cf);
        cf = fmaf(fv.z, lv.z, cf); cf = fmaf(fv.w, lv.w, cf);
      }
      val += ce + cf;
    }
  }
  float sum = val;
  #pragma unroll
  for (int off = 1; off < 64; off <<= 1) sum += __shfl_xor(sum, off, 64);
  float p_ = (tid < 64) ? val / (sum + cEPS) : 0.f;
  size_t base = (size_t)(dBase(ln - 1) + row) * cS;
  chart_p[base + tid] = p_;
  if (tid < 64) ps[tid] = p_;
  __syncthreads();
  float v = 0.f;
  for (int t = 0; t < 64; ++t) v = fmaf(GsumT[t * cS + tid], ps[t], v);
  chart_v[base + tid] = v;
}

// ---------------- combine: masses via lp.v dots, weighted relu(u+v+bm) -> chart_f ----------------
__global__ __launch_bounds__(256) void k_combine(const float* __restrict__ uv,
                                                 const float* __restrict__ chart_p,
                                                 const float* __restrict__ chart_v,
                                                 const float* __restrict__ bm,
                                                 __hip_bfloat16* __restrict__ cfh,
                                                 __hip_bfloat16* __restrict__ cfl,
                                                 int ln, int n) {
  __shared__ float lm[DMAX];
  __shared__ float red4[2][2];
  __shared__ long loff[DMAX];
  __shared__ long roff[DMAX];
  __shared__ long lpc[DMAX];
  __shared__ long vpc[DMAX];
  int row = blockIdx.x, tid = threadIdx.x;
  int D = ln - 1;
  int b = row / n, i = row - b * n;
  if (tid < D) {
    int dd = tid;
    long lc = dBase(dd) + (long)b * (cL - dd) + i;
    int dr = ln - dd - 2;
    long rc = dBase(dr) + (long)b * (cL - dr) + (i + dd + 1);
    loff[dd] = lc * 1024;        // u half
    roff[dd] = rc * 1024 + 512;  // v half
    lpc[dd] = lc * cS;
    vpc[dd] = rc * cS;
  }
  __syncthreads();
  int half = tid >> 7, l = tid & 127;
  for (int base0 = 0; base0 < D; base0 += 2) {
    int dd = base0 + half;
    float part = 0.f;
    if (dd < D)
      part = chart_p[lpc[dd] + l] * chart_v[vpc[dd] + l];
    #pragma unroll
    for (int off = 1; off < 64; off <<= 1) part += __shfl_xor(part, off, 64);
    if ((tid & 63) == 0) red4[half][(tid >> 6) & 1] = part;
    __syncthreads();
    if (tid < 2 && base0 + tid < D) lm[base0 + tid] = red4[tid][0] + red4[tid][1];
    __syncthreads();
  }
  float msum = 0.f;
  for (int dd = 0; dd < D; ++dd) msum += lm[dd];
  float inv = 1.f / (msum + cEPS);
  size_t outbase = (size_t)(dBase(ln - 1) + row) * cSD;
  for (int h = tid; h < cSD; h += 256) {
    float bmh = bm[h];
    float acc = 0.f;
    for (int dd = 0; dd < D; ++dd) {
      float fe = uv[loff[dd] + h] + uv[roff[dd] + h] + bmh;
      acc = fmaf(lm[dd], fmaxf(fe, 0.f), acc);
    }
    float v = acc * inv;
    __hip_bfloat16 hh, ll;
    split_bf16(v, hh, ll);
    cfh[outbase + h] = hh;
    cfl[outbase + h] = ll;
  }
}

// ---------------- root ----------------
__global__ void k_root(const float* __restrict__ chart_p,
                       const __hip_bfloat16* __restrict__ cfh,
                       const __hip_bfloat16* __restrict__ cfl,
                       const float* __restrict__ starts,
                       float* __restrict__ out) {
  __shared__ float red[2];
  int b = blockIdx.x, tid = threadIdx.x; // 128
  long cell = dBase(cL - 1) + b; // width 1 at diag L-1
  float v = chart_p[cell * cS + tid] * starts[tid];
  #pragma unroll
  for (int off = 1; off < 64; off <<= 1) v += __shfl_xor(v, off, 64);
  if ((tid & 63) == 0) red[tid >> 6] = v;
  __syncthreads();
  float score = red[0] + red[1];
  size_t fbase = (size_t)cell * cSD;
  for (int h = tid; h < cSD; h += 128) {
    float f = __bfloat162float(cfh[fbase + h]) + __bfloat162float(cfl[fbase + h]);
    out[(size_t)b * cSD + h] = f * score;
  }
}

extern "C" void kernel_launch(void* const* d_in, const int* in_sizes, int n_in,
                              void* d_out, int out_size, void* d_ws, size_t ws_size,
                              hipStream_t stream) {
  const int* word = (const int*)d_in[0];
  const float* WE = (const float*)d_in[1];
  const float* preterm = (const float*)d_in[2];
  const float* G = (const float*)d_in[3];
  const float* starts = (const float*)d_in[4];
  const float* Wp = (const float*)d_in[5];
  const float* bp = (const float*)d_in[6];
  const float* Wm = (const float*)d_in[7];
  const float* bm = (const float*)d_in[8];
  float* out = (float*)d_out;
  float* ws = (float*)d_ws;

  size_t off = 0;
  float* chart_p = ws + off; off += (size_t)TRIC * cS;           // 17.3 MB
  float* chart_v = ws + off; off += (size_t)TRIC * cS;           // 17.3 MB
  __hip_bfloat16* cfh = (__hip_bfloat16*)(ws + off); off += (size_t)TRIC * cSD / 2; // 34.6 MB
  __hip_bfloat16* cfl = (__hip_bfloat16*)(ws + off); off += (size_t)TRIC * cSD / 2; // 34.6 MB
  float* Gll = ws + off; off += (size_t)cKQ * cNT;               // 1 MB
  float* Ghh = ws + off; off += (size_t)cKQ * cNT;               // 1 MB
  float* GsumT = ws + off; off += cS * cS;
  float* e_arr = ws + off; off += (size_t)2048 * 4096;           // 33.5 MB
  float* f_arr = ws + off; off += (size_t)2048 * 4096;           // 33.5 MB
  __hip_bfloat16* WmTh = (__hip_bfloat16*)(ws + off); off += (size_t)cSD * 1024 / 2;
  __hip_bfloat16* WmTl = (__hip_bfloat16*)(ws + off); off += (size_t)cSD * 1024 / 2;
  float* uv = ws + off; off += (size_t)TRIC * 1024;              // 138.4 MB packed

  size_t avail = ws_size / sizeof(float) > off ? ws_size / sizeof(float) - off : 0;
  long perRow = cKQ + KS * cNT; // 6144 floats/row
  int CH = (int)(avail / perRow);
  if (CH > 1984) CH = 1984;
  CH &= ~127;
  if (CH < 128) CH = 128;
  int CHpad = CH;
  float* Obuf = ws + off; off += (size_t)CHpad * cKQ;
  float* scoresP = ws + off; off += (size_t)CHpad * KS * cNT;

  auto hdB = [](int d) { return (long)cB * ((long)d * cL - (long)d * (d - 1) / 2); };

  k_prep_g<<<(cS * cS) / 256, 256, 0, stream>>>(G, Gll, Ghh, GsumT);
  k_prep_wmt<<<(1024 * 512) / 256, 256, 0, stream>>>(Wm, WmTh, WmTl);
  k_diag<<<cB * cL, 128, 0, stream>>>(word, preterm, GsumT, chart_p, chart_v);
  k_prep_e<<<dim3(2048 / 64, 4096 / 64), 256, 0, stream>>>(chart_p, G, e_arr);
  k_prep_f<<<dim3(2048 / 8, 4), 256, 0, stream>>>(chart_p, G, f_arr);
  k_feat0<<<dim3((cB * cL) / 64, cSD / 64), 256, 0, stream>>>(word, WE, Wp, bp, cfh, cfl);
  // u,v for diagonal 0 (2048 cells)
  k_uv_mfma<<<dim3(1024 / 128, 2048 / 128), 256, 0, stream>>>(cfh, cfl, WmTh, WmTl, uv,
                                                              0L, cB * cL);

  for (int ln = 2; ln <= cL; ++ln) {
    int n = cL - ln + 1, Bn = cB * n;
    int useGemm = (ln == 2 || ln >= 4) ? 1 : 0;
    int useEF = (ln >= 3) ? 1 : 0;
    for (int cs = 0; cs < Bn; cs += CH) {
      int rows = (Bn - cs) < CH ? (Bn - cs) : CH;
      int gx = (rows + 127) / 128;
      if (useGemm) {
        if (ln == 2)
          k_outer<<<rows, 256, 0, stream>>>(chart_p, Obuf, ln, n, cs, 0, 0, 64, 64);
        else
          k_outer<<<rows, 256, 0, stream>>>(chart_p, Obuf, ln, n, cs, 1, ln - 3, 0, 0);
        k_scores<<<dim3(gx, KS), 256, 0, stream>>>(Obuf, (ln == 2) ? Ghh : Gll,
                                                   scoresP, CHpad, rows);
      }
      k_normp<<<rows, 128, 0, stream>>>(scoresP, e_arr, f_arr, GsumT, chart_p, chart_v,
                                        ln, n, CHpad, cs, useGemm, useEF);
    }
    k_combine<<<Bn, 256, 0, stream>>>(uv, chart_p, chart_v, bm, cfh, cfl, ln, n);
    if (ln < cL) {
      int padM = (Bn + 127) & ~127;
      k_uv_mfma<<<dim3(1024 / 128, padM / 128), 256, 0, stream>>>(cfh, cfl, WmTh, WmTl, uv,
                                                                  hdB(ln - 1), Bn);
    }
  }

  k_root<<<cB, 128, 0, stream>>>(chart_p, cfh, cfl, starts, out);
}

// Round 3
// 2252.094 us; speedup vs baseline: 1.5757x; 1.1013x over previous
//
#include <hip/hip_runtime.h>
#include <hip/hip_bf16.h>

// CYK forward. p-chain fp32; f-chain GEMM bf16x3 MFMA.
// Round 10: launch-graph compaction. Dependency analysis shows
// k_combine(ln) ⟂ k_normp(ln) and {k_uv(diag ln-1), k_outer(ln+1)} ⟂ each
// other and only need state available after k_np_comb(ln). Per-iteration
// launches 5 -> 3 (~160 -> ~98 dispatches): [k_scores] -> [k_np_comb] ->
// [k_uv_outer]. normp role lane-parallelized 4x (e/f + scoresP streams
// split over 4 x 64-lane groups, LDS tree). k_scores K-split 32 -> 16
// (halves scoresP partial traffic, grid still >= 256 blocks at full rows).
// Single chunk (CH=1984 >= max Bn; ws measured 409.6 MB via harness fill).

typedef __attribute__((ext_vector_type(8))) short short8;
typedef __attribute__((ext_vector_type(4))) float f32x4;

constexpr int cB = 64, cL = 32, cNT = 64, cS = 128, cV = 50000;
constexpr int cEMB = 512, cSD = 512, cKQ = 4096; // quadrant k
constexpr int DMAX = 31, KS = 16;                // k-slice = 256
constexpr float cEPS = 1e-9f;
constexpr long TRIC = (long)cB * (cL * (cL + 1) / 2); // 33792 packed cells

__device__ __forceinline__ long dBase(int d) {
  return (long)cB * ((long)d * cL - ((long)d * (d - 1)) / 2);
}

__device__ __forceinline__ void split_bf16(float x, __hip_bfloat16& h, __hip_bfloat16& l) {
  h = __float2bfloat16(x);
  l = __float2bfloat16(x - __bfloat162float(h));
}

// ---------------- G quadrant permutes + Gsum2T ----------------
__global__ __launch_bounds__(256) void k_prep_g(const float* __restrict__ G,
                                                float* __restrict__ Gll,
                                                float* __restrict__ Ghh,
                                                float* __restrict__ GsumT) {
  int idx = blockIdx.x * 256 + threadIdx.x; // s*128+t
  int s = idx >> 7, t = idx & 127;
  bool lo = (s < 64) && (t < 64);
  bool hi = (s >= 64) && (t >= 64);
  int pl = s * 64 + t;                  // valid when lo
  int ph = (s - 64) * 64 + (t - 64);    // valid when hi
  float accum = 0.f;
  for (int a = 0; a < cNT; ++a) {
    float g = G[(size_t)a * 16384 + idx];
    accum += g;
    if (lo) Gll[(size_t)pl * cNT + a] = g;
    if (hi) Ghh[(size_t)ph * cNT + a] = g;
  }
  GsumT[t * cS + s] = accum;
}

// ---------------- WmT hi/lo split, layout [nn<1024][k<512] ----------------
__global__ __launch_bounds__(256) void k_prep_wmt(const float* __restrict__ Wm,
                                                  __hip_bfloat16* __restrict__ WmTh,
                                                  __hip_bfloat16* __restrict__ WmTl) {
  int idx = blockIdx.x * 256 + threadIdx.x; // nn*512 + k
  int k = idx & 511, nn = idx >> 9;
  int krow = k + ((nn >= 512) ? 512 : 0);
  float v = Wm[(size_t)krow * cSD + (nn & 511)];
  __hip_bfloat16 h, l;
  split_bf16(v, h, l);
  WmTh[idx] = h;
  WmTl[idx] = l;
}

// ---------------- diagonal 0 of chart_p + chart_v ----------------
__global__ void k_diag(const int* __restrict__ word,
                       const float* __restrict__ preterm,
                       const float* __restrict__ GsumT,
                       float* __restrict__ chart_p,
                       float* __restrict__ chart_v) {
  __shared__ float ps[128];
  int row = blockIdx.x;  // packed diag-0 cell = b*L + pos
  int tid = threadIdx.x; // 0..127
  int w = word[row];
  float val = (tid >= 64) ? preterm[(size_t)(tid - 64) * cV + w] : 0.f;
  float sum = val;
  #pragma unroll
  for (int off = 1; off < 64; off <<= 1) sum += __shfl_xor(sum, off, 64);
  float p_ = (tid >= 64) ? val / (sum + cEPS) : 0.f;
  size_t base = (size_t)row * cS;
  chart_p[base + tid] = p_;
  ps[tid] = p_;
  __syncthreads();
  float v = 0.f;
  for (int t = 64; t < 128; ++t) v = fmaf(GsumT[t * cS + tid], ps[t], v);
  chart_v[base + tid] = v;
}

// ---------------- fp32 GEMM micro ----------------
__device__ __forceinline__ void micro16(const float (*As)[68], const float (*Bs)[68],
                                        int r0, int c0, float acc[4][4]) {
  #pragma unroll
  for (int k = 0; k < 16; ++k) {
    float4 a4 = *(const float4*)&As[k][r0];
    float4 b4 = *(const float4*)&Bs[k][c0];
    float ar[4] = {a4.x, a4.y, a4.z, a4.w};
    float br[4] = {b4.x, b4.y, b4.z, b4.w};
    #pragma unroll
    for (int i = 0; i < 4; ++i)
      #pragma unroll
      for (int j = 0; j < 4; ++j)
        acc[i][j] = fmaf(ar[i], br[j], acc[i][j]);
  }
}

// ---------------- e table ----------------
__global__ __launch_bounds__(256) void k_prep_e(const float* __restrict__ chart_p,
                                                const float* __restrict__ G,
                                                float* __restrict__ e_arr) {
  __shared__ float As[16][68];
  __shared__ float Bs[16][68];
  int tid = threadIdx.x;
  int rowTile = blockIdx.x * 64;
  int n0 = blockIdx.y * 64; // c-range = one a, t in [0,64)
  int a = n0 >> 6;
  int lr = tid >> 2, lk = (tid & 3) << 2;
  int bk = tid >> 4, bn = (tid & 15) << 2;
  int r0 = (tid >> 4) << 2, c0 = (tid & 15) << 2;
  float acc[4][4] = {};
  for (int kb = 0; kb < 64; kb += 16) {
    float4 av = *(const float4*)(chart_p + (size_t)(rowTile + lr) * cS + 64 + kb + lk);
    float4 bv = *(const float4*)(G + (size_t)a * 16384 + (size_t)(64 + kb + bk) * 128 + bn);
    __syncthreads();
    As[lk + 0][lr] = av.x; As[lk + 1][lr] = av.y;
    As[lk + 2][lr] = av.z; As[lk + 3][lr] = av.w;
    *(float4*)&Bs[bk][bn] = bv;
    __syncthreads();
    micro16(As, Bs, r0, c0, acc);
  }
  #pragma unroll
  for (int i = 0; i < 4; ++i) {
    float4 o = {acc[i][0], acc[i][1], acc[i][2], acc[i][3]};
    *(float4*)&e_arr[(size_t)(rowTile + r0 + i) * 4096 + n0 + c0] = o;
  }
}

// ---------------- f table ----------------
__global__ __launch_bounds__(256) void k_prep_f(const float* __restrict__ chart_p,
                                                const float* __restrict__ G,
                                                float* __restrict__ f_arr) {
  __shared__ float ph[8][64];
  int tid = threadIdx.x;
  int cell0 = blockIdx.x * 8;
  for (int v = tid; v < 512; v += 256) {
    int cc = v >> 6, t = v & 63;
    ph[cc][t] = chart_p[(size_t)(cell0 + cc) * cS + 64 + t];
  }
  __syncthreads();
  int oo0 = blockIdx.y * 4;
  for (int oo = oo0; oo < oo0 + 4; ++oo) {
    int out_id = oo * 256 + tid; // a*64 + s
    int a = out_id >> 6, s = out_id & 63;
    const float* gb = G + (size_t)a * 16384 + (size_t)s * 128 + 64;
    float acc[8] = {};
    #pragma unroll 4
    for (int ch = 0; ch < 16; ++ch) {
      float4 g4 = *(const float4*)(gb + ch * 4);
      #pragma unroll
      for (int cc = 0; cc < 8; ++cc) {
        float4 p4 = *(const float4*)&ph[cc][ch * 4];
        acc[cc] = fmaf(g4.x, p4.x, acc[cc]);
        acc[cc] = fmaf(g4.y, p4.y, acc[cc]);
        acc[cc] = fmaf(g4.z, p4.z, acc[cc]);
        acc[cc] = fmaf(g4.w, p4.w, acc[cc]);
      }
    }
    #pragma unroll
    for (int cc = 0; cc < 8; ++cc)
      f_arr[(size_t)(cell0 + cc) * 4096 + out_id] = acc[cc];
  }
}

// ---------------- feat0 -> hi/lo planes (diag-0 cells) ----------------
__global__ __launch_bounds__(256) void k_feat0(const int* __restrict__ word,
                                               const float* __restrict__ WE,
                                               const float* __restrict__ Wp,
                                               const float* __restrict__ bp,
                                               __hip_bfloat16* __restrict__ cfh,
                                               __hip_bfloat16* __restrict__ cfl) {
  __shared__ float As[16][68];
  __shared__ float Bs[16][68];
  int tid = threadIdx.x;
  int rowTile = blockIdx.x * 64;
  int n0 = blockIdx.y * 64;
  int lr = tid >> 2, lk = (tid & 3) << 2;
  int bk = tid >> 4, bn = (tid & 15) << 2;
  int r0 = (tid >> 4) << 2, c0 = (tid & 15) << 2;
  const float* ap = WE + (size_t)word[rowTile + lr] * cEMB;
  float acc[4][4] = {};
  for (int kb = 0; kb < cEMB; kb += 16) {
    float4 av = *(const float4*)(ap + kb + lk);
    float4 bv = *(const float4*)(Wp + (size_t)(kb + bk) * cSD + n0 + bn);
    __syncthreads();
    As[lk + 0][lr] = av.x; As[lk + 1][lr] = av.y;
    As[lk + 2][lr] = av.z; As[lk + 3][lr] = av.w;
    *(float4*)&Bs[bk][bn] = bv;
    __syncthreads();
    micro16(As, Bs, r0, c0, acc);
  }
  float4 bpv = *(const float4*)(bp + n0 + c0);
  float bpr[4] = {bpv.x, bpv.y, bpv.z, bpv.w};
  #pragma unroll
  for (int i = 0; i < 4; ++i) {
    int row = rowTile + r0 + i; // packed diag-0 cell index
    size_t base = (size_t)row * cSD + n0 + c0;
    #pragma unroll
    for (int e = 0; e < 4; ++e) {
      float v = fmaxf(acc[i][e] + bpr[e], 0.f);
      __hip_bfloat16 h, l;
      split_bf16(v, h, l);
      cfh[base + e] = h;
      cfl[base + e] = l;
    }
  }
}

// ---------------- fused: uv GEMM (diag d) + outer-product (next ln) ----------------
// Role A (bid < uvBlocks): bf16x3 MFMA uv GEMM, 128x128 tiles, K=512.
// Role B: quadrant outer-product O[row][4096] for the NEXT diagonal's scores.
// Legal because outer(ln+1) reads chart_p diagonals <= ln-2 only.
__global__ __launch_bounds__(256) void k_uv_outer(
    const __hip_bfloat16* __restrict__ cfh, const __hip_bfloat16* __restrict__ cfl,
    const __hip_bfloat16* __restrict__ WmTh, const __hip_bfloat16* __restrict__ WmTl,
    float* __restrict__ uv, long uvCellBase, int uvM, int uvBlocks,
    const float* __restrict__ chart_p, float* __restrict__ Obuf,
    int oln, int on, int odlo, int odhi, int osoff, int otoff) {
  __shared__ __align__(16) char smraw[40960];
  int bid = blockIdx.x;
  int tid = threadIdx.x;
  if (bid < uvBlocks) {
    // ======== uv GEMM role ========
    short* Ash = (short*)smraw;              // [2*128][40]
    short* Bsh = (short*)(smraw + 20480);    // [2*128][40]
    int colTile = (bid & 7) << 7;
    int rowTile = (bid >> 3) << 7;
    int m0 = tid >> 2, kq8 = (tid & 3) * 8;

    long offA[2];
    #pragma unroll
    for (int h = 0; h < 2; ++h) {
      int row = rowTile + m0 + h * 64;
      if (row >= uvM) row = uvM - 1;
      offA[h] = (uvCellBase + row) * cSD;
    }
    long offB0 = (long)(colTile + m0) * 512;
    long offB1 = (long)(colTile + m0 + 64) * 512;

    f32x4 acc[4][4];
    f32x4 zero = {0.f, 0.f, 0.f, 0.f};
    #pragma unroll
    for (int a_ = 0; a_ < 4; ++a_)
      #pragma unroll
      for (int b_ = 0; b_ < 4; ++b_) acc[a_][b_] = zero;

    int lane = tid & 63, wid = tid >> 6;
    int wm = wid >> 1, wn = wid & 1;
    int fr = lane & 15, fq = lane >> 4;

    int4 pA0h = *(const int4*)(const void*)(cfh + offA[0] + kq8);
    int4 pA1h = *(const int4*)(const void*)(cfh + offA[1] + kq8);
    int4 pA0l = *(const int4*)(const void*)(cfl + offA[0] + kq8);
    int4 pA1l = *(const int4*)(const void*)(cfl + offA[1] + kq8);
    int4 pB0h = *(const int4*)(const void*)(WmTh + offB0 + kq8);
    int4 pB1h = *(const int4*)(const void*)(WmTh + offB1 + kq8);
    int4 pB0l = *(const int4*)(const void*)(WmTl + offB0 + kq8);
    int4 pB1l = *(const int4*)(const void*)(WmTl + offB1 + kq8);

    for (int kb = 0; kb < 512; kb += 32) {
      __syncthreads();
      *(int4*)&Ash[(0 * 128 + m0) * 40 + kq8] = pA0h;
      *(int4*)&Ash[(0 * 128 + m0 + 64) * 40 + kq8] = pA1h;
      *(int4*)&Ash[(1 * 128 + m0) * 40 + kq8] = pA0l;
      *(int4*)&Ash[(1 * 128 + m0 + 64) * 40 + kq8] = pA1l;
      *(int4*)&Bsh[(0 * 128 + m0) * 40 + kq8] = pB0h;
      *(int4*)&Bsh[(0 * 128 + m0 + 64) * 40 + kq8] = pB1h;
      *(int4*)&Bsh[(1 * 128 + m0) * 40 + kq8] = pB0l;
      *(int4*)&Bsh[(1 * 128 + m0 + 64) * 40 + kq8] = pB1l;
      __syncthreads();
      int kn = kb + 32;
      if (kn < 512) {
        pA0h = *(const int4*)(const void*)(cfh + offA[0] + kn + kq8);
        pA1h = *(const int4*)(const void*)(cfh + offA[1] + kn + kq8);
        pA0l = *(const int4*)(const void*)(cfl + offA[0] + kn + kq8);
        pA1l = *(const int4*)(const void*)(cfl + offA[1] + kn + kq8);
        pB0h = *(const int4*)(const void*)(WmTh + offB0 + kn + kq8);
        pB1h = *(const int4*)(const void*)(WmTh + offB1 + kn + kq8);
        pB0l = *(const int4*)(const void*)(WmTl + offB0 + kn + kq8);
        pB1l = *(const int4*)(const void*)(WmTl + offB1 + kn + kq8);
      }
      short8 af[2][4], bf[2][4];
      #pragma unroll
      for (int pl = 0; pl < 2; ++pl)
        #pragma unroll
        for (int mf = 0; mf < 4; ++mf)
          af[pl][mf] = *(const short8*)&Ash[(pl * 128 + wm * 64 + mf * 16 + fr) * 40 + fq * 8];
      #pragma unroll
      for (int pl = 0; pl < 2; ++pl)
        #pragma unroll
        for (int nf = 0; nf < 4; ++nf)
          bf[pl][nf] = *(const short8*)&Bsh[(pl * 128 + wn * 64 + nf * 16 + fr) * 40 + fq * 8];
      #pragma unroll
      for (int mf = 0; mf < 4; ++mf)
        #pragma unroll
        for (int nf = 0; nf < 4; ++nf) {
          acc[mf][nf] = __builtin_amdgcn_mfma_f32_16x16x32_bf16(af[0][mf], bf[0][nf], acc[mf][nf], 0, 0, 0);
          acc[mf][nf] = __builtin_amdgcn_mfma_f32_16x16x32_bf16(af[0][mf], bf[1][nf], acc[mf][nf], 0, 0, 0);
          acc[mf][nf] = __builtin_amdgcn_mfma_f32_16x16x32_bf16(af[1][mf], bf[0][nf], acc[mf][nf], 0, 0, 0);
        }
    }
    #pragma unroll
    for (int mf = 0; mf < 4; ++mf)
      #pragma unroll
      for (int r = 0; r < 4; ++r) {
        int row = rowTile + wm * 64 + mf * 16 + fq * 4 + r;
        if (row >= uvM) continue;
        float* op = uv + (uvCellBase + row) * 1024 + colTile + wn * 64;
        #pragma unroll
        for (int nf = 0; nf < 4; ++nf)
          op[nf * 16 + fr] = acc[mf][nf][r];
      }
  } else {
    // ======== outer-product role (for diagonal oln) ========
    float* lp = (float*)smraw;                  // [DMAX][64]
    float* rp = (float*)(smraw + DMAX * 64 * 4);
    int lr = bid - uvBlocks;
    int b = lr / on, i = lr - b * on;
    if (tid < 128) {
      int lane = tid & 63;
      for (int dd = odlo + (tid >> 6); dd <= odhi; dd += 2) {
        long lc = dBase(dd) + (long)b * (cL - dd) + i;
        lp[(dd - odlo) * 64 + lane] = chart_p[lc * cS + osoff + lane];
      }
    } else {
      int t2 = tid - 128;
      int lane = t2 & 63;
      for (int dd = odlo + (t2 >> 6); dd <= odhi; dd += 2) {
        int dr = oln - dd - 2;
        long rc = dBase(dr) + (long)b * (cL - dr) + (i + dd + 1);
        rp[(dd - odlo) * 64 + lane] = chart_p[rc * cS + otoff + lane];
      }
    }
    __syncthreads();
    float acc[16];
    #pragma unroll
    for (int j = 0; j < 16; ++j) acc[j] = 0.f;
    int s = tid >> 2, t0 = (tid & 3) << 4;
    int dcount = odhi - odlo + 1;
    for (int dd = 0; dd < dcount; ++dd) {
      float lps = lp[dd * 64 + s];
      #pragma unroll
      for (int qq = 0; qq < 4; ++qq) {
        float4 r4 = *(const float4*)&rp[dd * 64 + t0 + qq * 4];
        acc[qq * 4 + 0] = fmaf(lps, r4.x, acc[qq * 4 + 0]);
        acc[qq * 4 + 1] = fmaf(lps, r4.y, acc[qq * 4 + 1]);
        acc[qq * 4 + 2] = fmaf(lps, r4.z, acc[qq * 4 + 2]);
        acc[qq * 4 + 3] = fmaf(lps, r4.w, acc[qq * 4 + 3]);
      }
    }
    float* op = Obuf + (size_t)lr * cKQ + (size_t)tid * 16; // p = s*64+t
    #pragma unroll
    for (int j = 0; j < 4; ++j) {
      float4 o = {acc[j * 4 + 0], acc[j * 4 + 1], acc[j * 4 + 2], acc[j * 4 + 3]};
      *(float4*)&op[j * 4] = o;
    }
  }
}

// ---------------- scores GEMM: O(rows x 4096) @ Gq(4096 x 64), K-split 16 ----------------
__global__ __launch_bounds__(256) void k_scores(const float* __restrict__ O,
                                                const float* __restrict__ Gq,
                                                float* __restrict__ scoresP,
                                                int CHpad, int rows) {
  __shared__ float As[32][128];
  __shared__ float Bs[32][64];
  int tid = threadIdx.x;
  int rowTile = blockIdx.x * 128;
  int ks = blockIdx.y;       // 0..15
  int kstart = ks * 256;
  int sm = tid & 127, skq = (tid >> 7) * 16;
  int bq = tid >> 4, bn4 = (tid & 15) * 4;
  int m0 = (tid & 15) << 2, n0 = (tid >> 4) << 2;
  const float* ap = O + (size_t)(rowTile + sm) * cKQ + kstart + skq;
  float acc[8][4] = {};
  for (int kb = 0; kb < 256; kb += 32) {
    float4 a0 = *(const float4*)(ap + kb + 0);
    float4 a1 = *(const float4*)(ap + kb + 4);
    float4 a2 = *(const float4*)(ap + kb + 8);
    float4 a3 = *(const float4*)(ap + kb + 12);
    float4 b0 = *(const float4*)(Gq + (size_t)(kstart + kb + bq * 2) * cNT + bn4);
    float4 b1 = *(const float4*)(Gq + (size_t)(kstart + kb + bq * 2 + 1) * cNT + bn4);
    __syncthreads();
    As[skq + 0][sm] = a0.x; As[skq + 1][sm] = a0.y; As[skq + 2][sm] = a0.z; As[skq + 3][sm] = a0.w;
    As[skq + 4][sm] = a1.x; As[skq + 5][sm] = a1.y; As[skq + 6][sm] = a1.z; As[skq + 7][sm] = a1.w;
    As[skq + 8][sm] = a2.x; As[skq + 9][sm] = a2.y; As[skq + 10][sm] = a2.z; As[skq + 11][sm] = a2.w;
    As[skq + 12][sm] = a3.x; As[skq + 13][sm] = a3.y; As[skq + 14][sm] = a3.z; As[skq + 15][sm] = a3.w;
    *(float4*)&Bs[bq * 2][bn4] = b0;
    *(float4*)&Bs[bq * 2 + 1][bn4] = b1;
    __syncthreads();
    #pragma unroll
    for (int k = 0; k < 32; ++k) {
      float4 av0 = *(const float4*)&As[k][m0];
      float4 av1 = *(const float4*)&As[k][m0 + 64];
      float4 bv = *(const float4*)&Bs[k][n0];
      float ar[8] = {av0.x, av0.y, av0.z, av0.w, av1.x, av1.y, av1.z, av1.w};
      float br[4] = {bv.x, bv.y, bv.z, bv.w};
      #pragma unroll
      for (int i = 0; i < 8; ++i)
        #pragma unroll
        for (int j = 0; j < 4; ++j)
          acc[i][j] = fmaf(ar[i], br[j], acc[i][j]);
    }
  }
  #pragma unroll
  for (int i = 0; i < 8; ++i) {
    int row = rowTile + m0 + (i >> 2) * 64 + (i & 3);
    if (row < rows) {
      float4 o = {acc[i][0], acc[i][1], acc[i][2], acc[i][3]};
      *(float4*)&scoresP[((size_t)ks * CHpad + row) * cNT + n0] = o;
    }
  }
}

// ---------------- fused: normp (partial-reduce + e/f + normalize + chart_v)
//                  + combine (masses + weighted relu(u+v+bm) -> chart_f) ----------------
// Legal because combine(ln) reads only diagonals <= ln-2 while normp writes ln-1.
__global__ __launch_bounds__(256) void k_np_comb(
    const float* __restrict__ scoresP, const float* __restrict__ e_arr,
    const float* __restrict__ f_arr, const float* __restrict__ GsumT,
    float* __restrict__ chart_p, float* __restrict__ chart_v,
    const float* __restrict__ uv, const float* __restrict__ bm,
    __hip_bfloat16* __restrict__ cfh, __hip_bfloat16* __restrict__ cfl,
    int ln, int nn, int CHpad, int useGemm, int useEF, int Bn) {
  __shared__ float sP[128];
  __shared__ float part[4][64];
  __shared__ float ps[64];
  __shared__ float lm[DMAX];
  __shared__ float red4[2][2];
  __shared__ long loff[DMAX];
  __shared__ long roff[DMAX];
  __shared__ long lpcS[DMAX];
  __shared__ long vpcS[DMAX];
  int bid = blockIdx.x, tid = threadIdx.x;
  if (bid < Bn) {
    // ======== normp role (4-way lane-parallel) ========
    int row = bid;
    int b = row / nn, i = row - b * nn;
    if (useEF) {
      long c2 = dBase(ln - 2) + (long)b * (nn + 1); // width at diag ln-2 is nn+1
      if (tid < 64)
        sP[tid] = chart_p[(c2 + i + 1) * cS + tid];
      else if (tid < 128)
        sP[tid] = chart_p[(c2 + i) * cS + (tid - 64)];
      __syncthreads();
    }
    int a = tid & 63, g = tid >> 6; // 4 groups of 64 lanes
    float val = 0.f;
    if (useGemm) {
      #pragma unroll
      for (int ks = g * 4; ks < g * 4 + 4; ++ks)
        val += scoresP[((size_t)ks * CHpad + row) * cNT + a];
    }
    if (useEF) {
      const float4* e4 = (const float4*)&e_arr[((size_t)(b * cL + i) * 4096) + a * 64];
      const float4* f4 = (const float4*)&f_arr[((size_t)(b * cL + i + ln - 1) * 4096) + a * 64];
      const float4* sP4 = (const float4*)sP;
      #pragma unroll
      for (int q = g * 4; q < g * 4 + 4; ++q) {
        float4 ev = e4[q];
        float4 fv = f4[q];
        float4 rv = sP4[q];
        float4 lv = sP4[16 + q];
        val = fmaf(ev.x, rv.x, val); val = fmaf(ev.y, rv.y, val);
        val = fmaf(ev.z, rv.z, val); val = fmaf(ev.w, rv.w, val);
        val = fmaf(fv.x, lv.x, val); val = fmaf(fv.y, lv.y, val);
        val = fmaf(fv.z, lv.z, val); val = fmaf(fv.w, lv.w, val);
      }
    }
    part[g][a] = val;
    __syncthreads();
    size_t base = (size_t)(dBase(ln - 1) + row) * cS;
    if (tid < 64) {
      float v = part[0][a] + part[1][a] + part[2][a] + part[3][a];
      float sum = v;
      #pragma unroll
      for (int off = 1; off < 64; off <<= 1) sum += __shfl_xor(sum, off, 64);
      float p_ = v / (sum + cEPS);
      ps[a] = p_;
      chart_p[base + tid] = p_;
    } else if (tid < 128) {
      chart_p[base + tid] = 0.f;
    }
    __syncthreads();
    if (tid < 128) {
      float v = 0.f;
      for (int t = 0; t < 64; ++t) v = fmaf(GsumT[t * cS + tid], ps[t], v);
      chart_v[base + tid] = v;
    }
  } else {
    // ======== combine role ========
    int row = bid - Bn;
    int D = ln - 1;
    int b = row / nn, i = row - b * nn;
    if (tid < D) {
      int dd = tid;
      long lc = dBase(dd) + (long)b * (cL - dd) + i;
      int dr = ln - dd - 2;
      long rc = dBase(dr) + (long)b * (cL - dr) + (i + dd + 1);
      loff[dd] = lc * 1024;        // u half
      roff[dd] = rc * 1024 + 512;  // v half
      lpcS[dd] = lc * cS;
      vpcS[dd] = rc * cS;
    }
    __syncthreads();
    int half = tid >> 7, l = tid & 127;
    for (int base0 = 0; base0 < D; base0 += 2) {
      int dd = base0 + half;
      float prt = 0.f;
      if (dd < D)
        prt = chart_p[lpcS[dd] + l] * chart_v[vpcS[dd] + l];
      #pragma unroll
      for (int off = 1; off < 64; off <<= 1) prt += __shfl_xor(prt, off, 64);
      if ((tid & 63) == 0) red4[half][(tid >> 6) & 1] = prt;
      __syncthreads();
      if (tid < 2 && base0 + tid < D) lm[base0 + tid] = red4[tid][0] + red4[tid][1];
      __syncthreads();
    }
    float msum = 0.f;
    for (int dd = 0; dd < D; ++dd) msum += lm[dd];
    float inv = 1.f / (msum + cEPS);
    size_t outbase = (size_t)(dBase(ln - 1) + row) * cSD;
    for (int h = tid; h < cSD; h += 256) {
      float bmh = bm[h];
      float acc = 0.f;
      for (int dd = 0; dd < D; ++dd) {
        float fe = uv[loff[dd] + h] + uv[roff[dd] + h] + bmh;
        acc = fmaf(lm[dd], fmaxf(fe, 0.f), acc);
      }
      float v = acc * inv;
      __hip_bfloat16 hh, ll;
      split_bf16(v, hh, ll);
      cfh[outbase + h] = hh;
      cfl[outbase + h] = ll;
    }
  }
}

// ---------------- root ----------------
__global__ void k_root(const float* __restrict__ chart_p,
                       const __hip_bfloat16* __restrict__ cfh,
                       const __hip_bfloat16* __restrict__ cfl,
                       const float* __restrict__ starts,
                       float* __restrict__ out) {
  __shared__ float red[2];
  int b = blockIdx.x, tid = threadIdx.x; // 128
  long cell = dBase(cL - 1) + b; // width 1 at diag L-1
  float v = chart_p[cell * cS + tid] * starts[tid];
  #pragma unroll
  for (int off = 1; off < 64; off <<= 1) v += __shfl_xor(v, off, 64);
  if ((tid & 63) == 0) red[tid >> 6] = v;
  __syncthreads();
  float score = red[0] + red[1];
  size_t fbase = (size_t)cell * cSD;
  for (int h = tid; h < cSD; h += 128) {
    float f = __bfloat162float(cfh[fbase + h]) + __bfloat162float(cfl[fbase + h]);
    out[(size_t)b * cSD + h] = f * score;
  }
}

extern "C" void kernel_launch(void* const* d_in, const int* in_sizes, int n_in,
                              void* d_out, int out_size, void* d_ws, size_t ws_size,
                              hipStream_t stream) {
  const int* word = (const int*)d_in[0];
  const float* WE = (const float*)d_in[1];
  const float* preterm = (const float*)d_in[2];
  const float* G = (const float*)d_in[3];
  const float* starts = (const float*)d_in[4];
  const float* Wp = (const float*)d_in[5];
  const float* bp = (const float*)d_in[6];
  const float* Wm = (const float*)d_in[7];
  const float* bm = (const float*)d_in[8];
  float* out = (float*)d_out;
  float* ws = (float*)d_ws;

  size_t off = 0;
  float* chart_p = ws + off; off += (size_t)TRIC * cS;           // 17.3 MB
  float* chart_v = ws + off; off += (size_t)TRIC * cS;           // 17.3 MB
  __hip_bfloat16* cfh = (__hip_bfloat16*)(ws + off); off += (size_t)TRIC * cSD / 2; // 34.6 MB
  __hip_bfloat16* cfl = (__hip_bfloat16*)(ws + off); off += (size_t)TRIC * cSD / 2; // 34.6 MB
  float* Gll = ws + off; off += (size_t)cKQ * cNT;               // 1 MB
  float* Ghh = ws + off; off += (size_t)cKQ * cNT;               // 1 MB
  float* GsumT = ws + off; off += cS * cS;
  float* e_arr = ws + off; off += (size_t)2048 * 4096;           // 33.5 MB
  float* f_arr = ws + off; off += (size_t)2048 * 4096;           // 33.5 MB
  __hip_bfloat16* WmTh = (__hip_bfloat16*)(ws + off); off += (size_t)cSD * 1024 / 2;
  __hip_bfloat16* WmTl = (__hip_bfloat16*)(ws + off); off += (size_t)cSD * 1024 / 2;
  float* uv = ws + off; off += (size_t)TRIC * 1024;              // 138.4 MB packed

  int CHpad = 1984; // max Bn; ws measured 409.6 MB >> fixed 314 + 40.6 MB
  float* Obuf = ws + off; off += (size_t)CHpad * cKQ;            // 32.5 MB
  float* scoresP = ws + off; off += (size_t)CHpad * KS * cNT;    // 8.1 MB

  auto hdB = [](int d) { return (long)cB * ((long)d * cL - (long)d * (d - 1) / 2); };

  k_prep_g<<<(cS * cS) / 256, 256, 0, stream>>>(G, Gll, Ghh, GsumT);
  k_prep_wmt<<<(1024 * 512) / 256, 256, 0, stream>>>(Wm, WmTh, WmTl);
  k_diag<<<cB * cL, 128, 0, stream>>>(word, preterm, GsumT, chart_p, chart_v);
  k_prep_e<<<dim3(2048 / 64, 4096 / 64), 256, 0, stream>>>(chart_p, G, e_arr);
  k_prep_f<<<dim3(2048 / 8, 4), 256, 0, stream>>>(chart_p, G, f_arr);
  k_feat0<<<dim3((cB * cL) / 64, cSD / 64), 256, 0, stream>>>(word, WE, Wp, bp, cfh, cfl);
  // prologue: uv(diag 0, 2048 cells) + outer(ln=2)
  k_uv_outer<<<16 * 8 + 1984, 256, 0, stream>>>(cfh, cfl, WmTh, WmTl, uv, 0L, 2048, 128,
                                                chart_p, Obuf, 2, 31, 0, 0, 64, 64);

  for (int ln = 2; ln <= cL; ++ln) {
    int n = cL - ln + 1, Bn = cB * n;
    int useGemm = (ln == 2 || ln >= 4) ? 1 : 0;
    int useEF = (ln >= 3) ? 1 : 0;
    if (useGemm) {
      int gx = (Bn + 127) / 128;
      k_scores<<<dim3(gx, KS), 256, 0, stream>>>(Obuf, (ln == 2) ? Ghh : Gll,
                                                 scoresP, CHpad, Bn);
    }
    k_np_comb<<<2 * Bn, 256, 0, stream>>>(scoresP, e_arr, f_arr, GsumT, chart_p, chart_v,
                                          uv, bm, cfh, cfl, ln, n, CHpad, useGemm, useEF, Bn);
    // L3: uv for diag ln-1 (M = Bn) + outer for diagonal ln+1
    int uvRT = (ln < cL) ? (Bn + 127) / 128 : 0;
    int ln2 = ln + 1;
    int rows2 = (ln2 <= cL && ln2 >= 4) ? cB * (cL - ln2 + 1) : 0;
    if (uvRT > 0 || rows2 > 0)
      k_uv_outer<<<uvRT * 8 + rows2, 256, 0, stream>>>(
          cfh, cfl, WmTh, WmTl, uv, hdB(ln - 1), Bn, uvRT * 8,
          chart_p, Obuf, ln2, cL - ln2 + 1, 1, ln2 - 3, 0, 0);
  }

  k_root<<<cB, 128, 0, stream>>>(chart_p, cfh, cfl, starts, out);
}

// Round 4
// 1872.751 us; speedup vs baseline: 1.8949x; 1.2026x over previous
//
#include <hip/hip_runtime.h>
#include <hip/hip_bf16.h>

// CYK forward. p-chain fp32; f-chain GEMM bf16x3 MFMA.
// Round 11: 2-kernel iteration. Dependency re-analysis: outer(ln+1) and
// uv(diag ln-2) depend only on np_comb(ln-1), so X(ln) = scores(ln) ||
// uv(diag ln-2) || outer(ln+1) (triple-role), Y(ln) = normp || combine.
// Obuf double-buffered by ln parity (scores reads buf[ln&1], outer writes
// buf[(ln+1)&1]). combine mass loop: D/2-iter x 2-barrier -> one-shot
// 16-elem-slice scheme (2 barriers). ~70 dispatches (was ~100).

typedef __attribute__((ext_vector_type(8))) short short8;
typedef __attribute__((ext_vector_type(4))) float f32x4;

constexpr int cB = 64, cL = 32, cNT = 64, cS = 128, cV = 50000;
constexpr int cEMB = 512, cSD = 512, cKQ = 4096; // quadrant k
constexpr int DMAX = 31, KS = 16;                // k-slice = 256
constexpr int CHpad = 1984;
constexpr float cEPS = 1e-9f;
constexpr long TRIC = (long)cB * (cL * (cL + 1) / 2); // 33792 packed cells

__device__ __forceinline__ long dBase(int d) {
  return (long)cB * ((long)d * cL - ((long)d * (d - 1)) / 2);
}

__device__ __forceinline__ void split_bf16(float x, __hip_bfloat16& h, __hip_bfloat16& l) {
  h = __float2bfloat16(x);
  l = __float2bfloat16(x - __bfloat162float(h));
}

// ---------------- G quadrant permutes + Gsum2T ----------------
__global__ __launch_bounds__(256) void k_prep_g(const float* __restrict__ G,
                                                float* __restrict__ Gll,
                                                float* __restrict__ Ghh,
                                                float* __restrict__ GsumT) {
  int idx = blockIdx.x * 256 + threadIdx.x; // s*128+t
  int s = idx >> 7, t = idx & 127;
  bool lo = (s < 64) && (t < 64);
  bool hi = (s >= 64) && (t >= 64);
  int pl = s * 64 + t;
  int ph = (s - 64) * 64 + (t - 64);
  float accum = 0.f;
  for (int a = 0; a < cNT; ++a) {
    float g = G[(size_t)a * 16384 + idx];
    accum += g;
    if (lo) Gll[(size_t)pl * cNT + a] = g;
    if (hi) Ghh[(size_t)ph * cNT + a] = g;
  }
  GsumT[t * cS + s] = accum;
}

// ---------------- WmT hi/lo split, layout [nn<1024][k<512] ----------------
__global__ __launch_bounds__(256) void k_prep_wmt(const float* __restrict__ Wm,
                                                  __hip_bfloat16* __restrict__ WmTh,
                                                  __hip_bfloat16* __restrict__ WmTl) {
  int idx = blockIdx.x * 256 + threadIdx.x; // nn*512 + k
  int k = idx & 511, nn = idx >> 9;
  int krow = k + ((nn >= 512) ? 512 : 0);
  float v = Wm[(size_t)krow * cSD + (nn & 511)];
  __hip_bfloat16 h, l;
  split_bf16(v, h, l);
  WmTh[idx] = h;
  WmTl[idx] = l;
}

// ---------------- diagonal 0 of chart_p + chart_v ----------------
__global__ void k_diag(const int* __restrict__ word,
                       const float* __restrict__ preterm,
                       const float* __restrict__ GsumT,
                       float* __restrict__ chart_p,
                       float* __restrict__ chart_v) {
  __shared__ float ps[128];
  int row = blockIdx.x;  // packed diag-0 cell = b*L + pos
  int tid = threadIdx.x; // 0..127
  int w = word[row];
  float val = (tid >= 64) ? preterm[(size_t)(tid - 64) * cV + w] : 0.f;
  float sum = val;
  #pragma unroll
  for (int off = 1; off < 64; off <<= 1) sum += __shfl_xor(sum, off, 64);
  float p_ = (tid >= 64) ? val / (sum + cEPS) : 0.f;
  size_t base = (size_t)row * cS;
  chart_p[base + tid] = p_;
  ps[tid] = p_;
  __syncthreads();
  float v = 0.f;
  for (int t = 64; t < 128; ++t) v = fmaf(GsumT[t * cS + tid], ps[t], v);
  chart_v[base + tid] = v;
}

// ---------------- fp32 GEMM micro ----------------
__device__ __forceinline__ void micro16(const float (*As)[68], const float (*Bs)[68],
                                        int r0, int c0, float acc[4][4]) {
  #pragma unroll
  for (int k = 0; k < 16; ++k) {
    float4 a4 = *(const float4*)&As[k][r0];
    float4 b4 = *(const float4*)&Bs[k][c0];
    float ar[4] = {a4.x, a4.y, a4.z, a4.w};
    float br[4] = {b4.x, b4.y, b4.z, b4.w};
    #pragma unroll
    for (int i = 0; i < 4; ++i)
      #pragma unroll
      for (int j = 0; j < 4; ++j)
        acc[i][j] = fmaf(ar[i], br[j], acc[i][j]);
  }
}

// ---------------- e table ----------------
__global__ __launch_bounds__(256) void k_prep_e(const float* __restrict__ chart_p,
                                                const float* __restrict__ G,
                                                float* __restrict__ e_arr) {
  __shared__ float As[16][68];
  __shared__ float Bs[16][68];
  int tid = threadIdx.x;
  int rowTile = blockIdx.x * 64;
  int n0 = blockIdx.y * 64; // c-range = one a, t in [0,64)
  int a = n0 >> 6;
  int lr = tid >> 2, lk = (tid & 3) << 2;
  int bk = tid >> 4, bn = (tid & 15) << 2;
  int r0 = (tid >> 4) << 2, c0 = (tid & 15) << 2;
  float acc[4][4] = {};
  for (int kb = 0; kb < 64; kb += 16) {
    float4 av = *(const float4*)(chart_p + (size_t)(rowTile + lr) * cS + 64 + kb + lk);
    float4 bv = *(const float4*)(G + (size_t)a * 16384 + (size_t)(64 + kb + bk) * 128 + bn);
    __syncthreads();
    As[lk + 0][lr] = av.x; As[lk + 1][lr] = av.y;
    As[lk + 2][lr] = av.z; As[lk + 3][lr] = av.w;
    *(float4*)&Bs[bk][bn] = bv;
    __syncthreads();
    micro16(As, Bs, r0, c0, acc);
  }
  #pragma unroll
  for (int i = 0; i < 4; ++i) {
    float4 o = {acc[i][0], acc[i][1], acc[i][2], acc[i][3]};
    *(float4*)&e_arr[(size_t)(rowTile + r0 + i) * 4096 + n0 + c0] = o;
  }
}

// ---------------- f table ----------------
__global__ __launch_bounds__(256) void k_prep_f(const float* __restrict__ chart_p,
                                                const float* __restrict__ G,
                                                float* __restrict__ f_arr) {
  __shared__ float ph[8][64];
  int tid = threadIdx.x;
  int cell0 = blockIdx.x * 8;
  for (int v = tid; v < 512; v += 256) {
    int cc = v >> 6, t = v & 63;
    ph[cc][t] = chart_p[(size_t)(cell0 + cc) * cS + 64 + t];
  }
  __syncthreads();
  int oo0 = blockIdx.y * 4;
  for (int oo = oo0; oo < oo0 + 4; ++oo) {
    int out_id = oo * 256 + tid; // a*64 + s
    int a = out_id >> 6, s = out_id & 63;
    const float* gb = G + (size_t)a * 16384 + (size_t)s * 128 + 64;
    float acc[8] = {};
    #pragma unroll 4
    for (int ch = 0; ch < 16; ++ch) {
      float4 g4 = *(const float4*)(gb + ch * 4);
      #pragma unroll
      for (int cc = 0; cc < 8; ++cc) {
        float4 p4 = *(const float4*)&ph[cc][ch * 4];
        acc[cc] = fmaf(g4.x, p4.x, acc[cc]);
        acc[cc] = fmaf(g4.y, p4.y, acc[cc]);
        acc[cc] = fmaf(g4.z, p4.z, acc[cc]);
        acc[cc] = fmaf(g4.w, p4.w, acc[cc]);
      }
    }
    #pragma unroll
    for (int cc = 0; cc < 8; ++cc)
      f_arr[(size_t)(cell0 + cc) * 4096 + out_id] = acc[cc];
  }
}

// ---------------- feat0 -> hi/lo planes (diag-0 cells) ----------------
__global__ __launch_bounds__(256) void k_feat0(const int* __restrict__ word,
                                               const float* __restrict__ WE,
                                               const float* __restrict__ Wp,
                                               const float* __restrict__ bp,
                                               __hip_bfloat16* __restrict__ cfh,
                                               __hip_bfloat16* __restrict__ cfl) {
  __shared__ float As[16][68];
  __shared__ float Bs[16][68];
  int tid = threadIdx.x;
  int rowTile = blockIdx.x * 64;
  int n0 = blockIdx.y * 64;
  int lr = tid >> 2, lk = (tid & 3) << 2;
  int bk = tid >> 4, bn = (tid & 15) << 2;
  int r0 = (tid >> 4) << 2, c0 = (tid & 15) << 2;
  const float* ap = WE + (size_t)word[rowTile + lr] * cEMB;
  float acc[4][4] = {};
  for (int kb = 0; kb < cEMB; kb += 16) {
    float4 av = *(const float4*)(ap + kb + lk);
    float4 bv = *(const float4*)(Wp + (size_t)(kb + bk) * cSD + n0 + bn);
    __syncthreads();
    As[lk + 0][lr] = av.x; As[lk + 1][lr] = av.y;
    As[lk + 2][lr] = av.z; As[lk + 3][lr] = av.w;
    *(float4*)&Bs[bk][bn] = bv;
    __syncthreads();
    micro16(As, Bs, r0, c0, acc);
  }
  float4 bpv = *(const float4*)(bp + n0 + c0);
  float bpr[4] = {bpv.x, bpv.y, bpv.z, bpv.w};
  #pragma unroll
  for (int i = 0; i < 4; ++i) {
    int row = rowTile + r0 + i; // packed diag-0 cell index
    size_t base = (size_t)row * cSD + n0 + c0;
    #pragma unroll
    for (int e = 0; e < 4; ++e) {
      float v = fmaxf(acc[i][e] + bpr[e], 0.f);
      __hip_bfloat16 h, l;
      split_bf16(v, h, l);
      cfh[base + e] = h;
      cfl[base + e] = l;
    }
  }
}

// ---------------- X: triple role = scores GEMM | uv GEMM | outer-product ----------------
// scores: Oin(rows x 4096) @ Gq(4096 x 64), K-split KS, writes scoresP partials.
// uv:     bf16x3 MFMA 128x128 tiles K=512 over cells of one diagonal.
// outer:  quadrant outer-product O[row][4096] for diagonal oln -> Oout.
// Legality: all three depend only on np_comb(ln-1); Oin/Oout are distinct buffers.
__global__ __launch_bounds__(256) void k_X(
    const float* __restrict__ Oin, const float* __restrict__ Gq,
    float* __restrict__ scoresP, int gx, int sRows, int sB,
    const __hip_bfloat16* __restrict__ cfh, const __hip_bfloat16* __restrict__ cfl,
    const __hip_bfloat16* __restrict__ WmTh, const __hip_bfloat16* __restrict__ WmTl,
    float* __restrict__ uv, long uvCellBase, int uvM, int uB,
    const float* __restrict__ chart_p, float* __restrict__ Oout,
    int oln, int on, int odlo, int odhi, int osoff, int otoff) {
  __shared__ __align__(16) char smraw[40960];
  int bid = blockIdx.x;
  int tid = threadIdx.x;
  if (bid < sB) {
    // ======== scores role ========
    float (*As)[128] = (float (*)[128])smraw;            // [32][128]
    float (*Bs)[64] = (float (*)[64])(smraw + 16384);    // [32][64]
    int rt = bid % gx, ks = bid / gx;
    int rowTile = rt * 128;
    int kstart = ks * 256;
    int sm = tid & 127, skq = (tid >> 7) * 16;
    int bq = tid >> 4, bn4 = (tid & 15) * 4;
    int m0 = (tid & 15) << 2, n0 = (tid >> 4) << 2;
    const float* ap = Oin + (size_t)(rowTile + sm) * cKQ + kstart + skq;
    float acc[8][4] = {};
    for (int kb = 0; kb < 256; kb += 32) {
      float4 a0 = *(const float4*)(ap + kb + 0);
      float4 a1 = *(const float4*)(ap + kb + 4);
      float4 a2 = *(const float4*)(ap + kb + 8);
      float4 a3 = *(const float4*)(ap + kb + 12);
      float4 b0 = *(const float4*)(Gq + (size_t)(kstart + kb + bq * 2) * cNT + bn4);
      float4 b1 = *(const float4*)(Gq + (size_t)(kstart + kb + bq * 2 + 1) * cNT + bn4);
      __syncthreads();
      As[skq + 0][sm] = a0.x; As[skq + 1][sm] = a0.y; As[skq + 2][sm] = a0.z; As[skq + 3][sm] = a0.w;
      As[skq + 4][sm] = a1.x; As[skq + 5][sm] = a1.y; As[skq + 6][sm] = a1.z; As[skq + 7][sm] = a1.w;
      As[skq + 8][sm] = a2.x; As[skq + 9][sm] = a2.y; As[skq + 10][sm] = a2.z; As[skq + 11][sm] = a2.w;
      As[skq + 12][sm] = a3.x; As[skq + 13][sm] = a3.y; As[skq + 14][sm] = a3.z; As[skq + 15][sm] = a3.w;
      *(float4*)&Bs[bq * 2][bn4] = b0;
      *(float4*)&Bs[bq * 2 + 1][bn4] = b1;
      __syncthreads();
      #pragma unroll
      for (int k = 0; k < 32; ++k) {
        float4 av0 = *(const float4*)&As[k][m0];
        float4 av1 = *(const float4*)&As[k][m0 + 64];
        float4 bv = *(const float4*)&Bs[k][n0];
        float ar[8] = {av0.x, av0.y, av0.z, av0.w, av1.x, av1.y, av1.z, av1.w};
        float br[4] = {bv.x, bv.y, bv.z, bv.w};
        #pragma unroll
        for (int i = 0; i < 8; ++i)
          #pragma unroll
          for (int j = 0; j < 4; ++j)
            acc[i][j] = fmaf(ar[i], br[j], acc[i][j]);
      }
    }
    #pragma unroll
    for (int i = 0; i < 8; ++i) {
      int row = rowTile + m0 + (i >> 2) * 64 + (i & 3);
      if (row < sRows) {
        float4 o = {acc[i][0], acc[i][1], acc[i][2], acc[i][3]};
        *(float4*)&scoresP[((size_t)ks * CHpad + row) * cNT + n0] = o;
      }
    }
  } else if (bid < sB + uB) {
    // ======== uv GEMM role ========
    short* Ash = (short*)smraw;              // [2*128][40]
    short* Bsh = (short*)(smraw + 20480);    // [2*128][40]
    int ubid = bid - sB;
    int colTile = (ubid & 7) << 7;
    int rowTile = (ubid >> 3) << 7;
    int m0 = tid >> 2, kq8 = (tid & 3) * 8;

    long offA[2];
    #pragma unroll
    for (int h = 0; h < 2; ++h) {
      int row = rowTile + m0 + h * 64;
      if (row >= uvM) row = uvM - 1;
      offA[h] = (uvCellBase + row) * cSD;
    }
    long offB0 = (long)(colTile + m0) * 512;
    long offB1 = (long)(colTile + m0 + 64) * 512;

    f32x4 acc[4][4];
    f32x4 zero = {0.f, 0.f, 0.f, 0.f};
    #pragma unroll
    for (int a_ = 0; a_ < 4; ++a_)
      #pragma unroll
      for (int b_ = 0; b_ < 4; ++b_) acc[a_][b_] = zero;

    int lane = tid & 63, wid = tid >> 6;
    int wm = wid >> 1, wn = wid & 1;
    int fr = lane & 15, fq = lane >> 4;

    int4 pA0h = *(const int4*)(const void*)(cfh + offA[0] + kq8);
    int4 pA1h = *(const int4*)(const void*)(cfh + offA[1] + kq8);
    int4 pA0l = *(const int4*)(const void*)(cfl + offA[0] + kq8);
    int4 pA1l = *(const int4*)(const void*)(cfl + offA[1] + kq8);
    int4 pB0h = *(const int4*)(const void*)(WmTh + offB0 + kq8);
    int4 pB1h = *(const int4*)(const void*)(WmTh + offB1 + kq8);
    int4 pB0l = *(const int4*)(const void*)(WmTl + offB0 + kq8);
    int4 pB1l = *(const int4*)(const void*)(WmTl + offB1 + kq8);

    for (int kb = 0; kb < 512; kb += 32) {
      __syncthreads();
      *(int4*)&Ash[(0 * 128 + m0) * 40 + kq8] = pA0h;
      *(int4*)&Ash[(0 * 128 + m0 + 64) * 40 + kq8] = pA1h;
      *(int4*)&Ash[(1 * 128 + m0) * 40 + kq8] = pA0l;
      *(int4*)&Ash[(1 * 128 + m0 + 64) * 40 + kq8] = pA1l;
      *(int4*)&Bsh[(0 * 128 + m0) * 40 + kq8] = pB0h;
      *(int4*)&Bsh[(0 * 128 + m0 + 64) * 40 + kq8] = pB1h;
      *(int4*)&Bsh[(1 * 128 + m0) * 40 + kq8] = pB0l;
      *(int4*)&Bsh[(1 * 128 + m0 + 64) * 40 + kq8] = pB1l;
      __syncthreads();
      int kn = kb + 32;
      if (kn < 512) {
        pA0h = *(const int4*)(const void*)(cfh + offA[0] + kn + kq8);
        pA1h = *(const int4*)(const void*)(cfh + offA[1] + kn + kq8);
        pA0l = *(const int4*)(const void*)(cfl + offA[0] + kn + kq8);
        pA1l = *(const int4*)(const void*)(cfl + offA[1] + kn + kq8);
        pB0h = *(const int4*)(const void*)(WmTh + offB0 + kn + kq8);
        pB1h = *(const int4*)(const void*)(WmTh + offB1 + kn + kq8);
        pB0l = *(const int4*)(const void*)(WmTl + offB0 + kn + kq8);
        pB1l = *(const int4*)(const void*)(WmTl + offB1 + kn + kq8);
      }
      short8 af[2][4], bf[2][4];
      #pragma unroll
      for (int pl = 0; pl < 2; ++pl)
        #pragma unroll
        for (int mf = 0; mf < 4; ++mf)
          af[pl][mf] = *(const short8*)&Ash[(pl * 128 + wm * 64 + mf * 16 + fr) * 40 + fq * 8];
      #pragma unroll
      for (int pl = 0; pl < 2; ++pl)
        #pragma unroll
        for (int nf = 0; nf < 4; ++nf)
          bf[pl][nf] = *(const short8*)&Bsh[(pl * 128 + wn * 64 + nf * 16 + fr) * 40 + fq * 8];
      #pragma unroll
      for (int mf = 0; mf < 4; ++mf)
        #pragma unroll
        for (int nf = 0; nf < 4; ++nf) {
          acc[mf][nf] = __builtin_amdgcn_mfma_f32_16x16x32_bf16(af[0][mf], bf[0][nf], acc[mf][nf], 0, 0, 0);
          acc[mf][nf] = __builtin_amdgcn_mfma_f32_16x16x32_bf16(af[0][mf], bf[1][nf], acc[mf][nf], 0, 0, 0);
          acc[mf][nf] = __builtin_amdgcn_mfma_f32_16x16x32_bf16(af[1][mf], bf[0][nf], acc[mf][nf], 0, 0, 0);
        }
    }
    #pragma unroll
    for (int mf = 0; mf < 4; ++mf)
      #pragma unroll
      for (int r = 0; r < 4; ++r) {
        int row = rowTile + wm * 64 + mf * 16 + fq * 4 + r;
        if (row >= uvM) continue;
        float* op = uv + (uvCellBase + row) * 1024 + colTile + wn * 64;
        #pragma unroll
        for (int nf = 0; nf < 4; ++nf)
          op[nf * 16 + fr] = acc[mf][nf][r];
      }
  } else {
    // ======== outer-product role (for diagonal oln) ========
    float* lp = (float*)smraw;                  // [DMAX][64]
    float* rp = (float*)(smraw + DMAX * 64 * 4);
    int lr = bid - sB - uB;
    int b = lr / on, i = lr - b * on;
    if (tid < 128) {
      int lane = tid & 63;
      for (int dd = odlo + (tid >> 6); dd <= odhi; dd += 2) {
        long lc = dBase(dd) + (long)b * (cL - dd) + i;
        lp[(dd - odlo) * 64 + lane] = chart_p[lc * cS + osoff + lane];
      }
    } else {
      int t2 = tid - 128;
      int lane = t2 & 63;
      for (int dd = odlo + (t2 >> 6); dd <= odhi; dd += 2) {
        int dr = oln - dd - 2;
        long rc = dBase(dr) + (long)b * (cL - dr) + (i + dd + 1);
        rp[(dd - odlo) * 64 + lane] = chart_p[rc * cS + otoff + lane];
      }
    }
    __syncthreads();
    float acc[16];
    #pragma unroll
    for (int j = 0; j < 16; ++j) acc[j] = 0.f;
    int s = tid >> 2, t0 = (tid & 3) << 4;
    int dcount = odhi - odlo + 1;
    for (int dd = 0; dd < dcount; ++dd) {
      float lps = lp[dd * 64 + s];
      #pragma unroll
      for (int qq = 0; qq < 4; ++qq) {
        float4 r4 = *(const float4*)&rp[dd * 64 + t0 + qq * 4];
        acc[qq * 4 + 0] = fmaf(lps, r4.x, acc[qq * 4 + 0]);
        acc[qq * 4 + 1] = fmaf(lps, r4.y, acc[qq * 4 + 1]);
        acc[qq * 4 + 2] = fmaf(lps, r4.z, acc[qq * 4 + 2]);
        acc[qq * 4 + 3] = fmaf(lps, r4.w, acc[qq * 4 + 3]);
      }
    }
    float* op = Oout + (size_t)lr * cKQ + (size_t)tid * 16; // p = s*64+t
    #pragma unroll
    for (int j = 0; j < 4; ++j) {
      float4 o = {acc[j * 4 + 0], acc[j * 4 + 1], acc[j * 4 + 2], acc[j * 4 + 3]};
      *(float4*)&op[j * 4] = o;
    }
  }
}

// ---------------- Y: normp (reduce + e/f + normalize + chart_v) | combine ----------------
__global__ __launch_bounds__(256) void k_Y(
    const float* __restrict__ scoresP, const float* __restrict__ e_arr,
    const float* __restrict__ f_arr, const float* __restrict__ GsumT,
    float* __restrict__ chart_p, float* __restrict__ chart_v,
    const float* __restrict__ uv, const float* __restrict__ bm,
    __hip_bfloat16* __restrict__ cfh, __hip_bfloat16* __restrict__ cfl,
    int ln, int nn, int useGemm, int useEF, int Bn) {
  __shared__ float sP[128];
  __shared__ float part[4][64];
  __shared__ float ps[64];
  __shared__ float lm[DMAX];
  __shared__ float part8[32][8];
  __shared__ long loff[DMAX];
  __shared__ long roff[DMAX];
  __shared__ long lpcS[DMAX];
  __shared__ long vpcS[DMAX];
  int bid = blockIdx.x, tid = threadIdx.x;
  if (bid < Bn) {
    // ======== normp role (4-way lane-parallel) ========
    int row = bid;
    int b = row / nn, i = row - b * nn;
    if (useEF) {
      long c2 = dBase(ln - 2) + (long)b * (nn + 1); // width at diag ln-2 is nn+1
      if (tid < 64)
        sP[tid] = chart_p[(c2 + i + 1) * cS + tid];
      else if (tid < 128)
        sP[tid] = chart_p[(c2 + i) * cS + (tid - 64)];
      __syncthreads();
    }
    int a = tid & 63, g = tid >> 6; // 4 groups of 64 lanes
    float val = 0.f;
    if (useGemm) {
      #pragma unroll
      for (int ks = g * 4; ks < g * 4 + 4; ++ks)
        val += scoresP[((size_t)ks * CHpad + row) * cNT + a];
    }
    if (useEF) {
      const float4* e4 = (const float4*)&e_arr[((size_t)(b * cL + i) * 4096) + a * 64];
      const float4* f4 = (const float4*)&f_arr[((size_t)(b * cL + i + ln - 1) * 4096) + a * 64];
      const float4* sP4 = (const float4*)sP;
      #pragma unroll
      for (int q = g * 4; q < g * 4 + 4; ++q) {
        float4 ev = e4[q];
        float4 fv = f4[q];
        float4 rv = sP4[q];
        float4 lv = sP4[16 + q];
        val = fmaf(ev.x, rv.x, val); val = fmaf(ev.y, rv.y, val);
        val = fmaf(ev.z, rv.z, val); val = fmaf(ev.w, rv.w, val);
        val = fmaf(fv.x, lv.x, val); val = fmaf(fv.y, lv.y, val);
        val = fmaf(fv.z, lv.z, val); val = fmaf(fv.w, lv.w, val);
      }
    }
    part[g][a] = val;
    __syncthreads();
    size_t base = (size_t)(dBase(ln - 1) + row) * cS;
    if (tid < 64) {
      float v = part[0][a] + part[1][a] + part[2][a] + part[3][a];
      float sum = v;
      #pragma unroll
      for (int off = 1; off < 64; off <<= 1) sum += __shfl_xor(sum, off, 64);
      float p_ = v / (sum + cEPS);
      ps[a] = p_;
      chart_p[base + tid] = p_;
    } else if (tid < 128) {
      chart_p[base + tid] = 0.f;
    }
    __syncthreads();
    if (tid < 128) {
      float v = 0.f;
      for (int t = 0; t < 64; ++t) v = fmaf(GsumT[t * cS + tid], ps[t], v);
      chart_v[base + tid] = v;
    }
  } else {
    // ======== combine role ========
    int row = bid - Bn;
    int D = ln - 1;
    int b = row / nn, i = row - b * nn;
    if (tid < D) {
      int dd = tid;
      long lc = dBase(dd) + (long)b * (cL - dd) + i;
      int dr = ln - dd - 2;
      long rc = dBase(dr) + (long)b * (cL - dr) + (i + dd + 1);
      loff[dd] = lc * 1024;        // u half
      roff[dd] = rc * 1024 + 512;  // v half
      lpcS[dd] = lc * cS;
      vpcS[dd] = rc * cS;
    }
    __syncthreads();
    // masses: one-shot 16-elem slices (thread tid -> mass dd=tid>>3, slice (tid&7)*16)
    int dd8 = tid >> 3, sl = (tid & 7) << 4;
    float prt = 0.f;
    if (dd8 < D) {
      const float* pp = &chart_p[lpcS[dd8] + sl];
      const float* vv = &chart_v[vpcS[dd8] + sl];
      #pragma unroll
      for (int q = 0; q < 4; ++q) {
        float4 p4 = *(const float4*)(pp + q * 4);
        float4 v4 = *(const float4*)(vv + q * 4);
        prt = fmaf(p4.x, v4.x, prt); prt = fmaf(p4.y, v4.y, prt);
        prt = fmaf(p4.z, v4.z, prt); prt = fmaf(p4.w, v4.w, prt);
      }
    }
    part8[dd8][tid & 7] = prt;
    __syncthreads();
    if (tid < D) {
      float s = 0.f;
      #pragma unroll
      for (int j = 0; j < 8; ++j) s += part8[tid][j];
      lm[tid] = s;
    }
    __syncthreads();
    float msum = 0.f;
    for (int dd = 0; dd < D; ++dd) msum += lm[dd];
    float inv = 1.f / (msum + cEPS);
    size_t outbase = (size_t)(dBase(ln - 1) + row) * cSD;
    for (int h = tid; h < cSD; h += 256) {
      float bmh = bm[h];
      float acc = 0.f;
      for (int dd = 0; dd < D; ++dd) {
        float fe = uv[loff[dd] + h] + uv[roff[dd] + h] + bmh;
        acc = fmaf(lm[dd], fmaxf(fe, 0.f), acc);
      }
      float v = acc * inv;
      __hip_bfloat16 hh, ll;
      split_bf16(v, hh, ll);
      cfh[outbase + h] = hh;
      cfl[outbase + h] = ll;
    }
  }
}

// ---------------- root ----------------
__global__ void k_root(const float* __restrict__ chart_p,
                       const __hip_bfloat16* __restrict__ cfh,
                       const __hip_bfloat16* __restrict__ cfl,
                       const float* __restrict__ starts,
                       float* __restrict__ out) {
  __shared__ float red[2];
  int b = blockIdx.x, tid = threadIdx.x; // 128
  long cell = dBase(cL - 1) + b; // width 1 at diag L-1
  float v = chart_p[cell * cS + tid] * starts[tid];
  #pragma unroll
  for (int off = 1; off < 64; off <<= 1) v += __shfl_xor(v, off, 64);
  if ((tid & 63) == 0) red[tid >> 6] = v;
  __syncthreads();
  float score = red[0] + red[1];
  size_t fbase = (size_t)cell * cSD;
  for (int h = tid; h < cSD; h += 128) {
    float f = __bfloat162float(cfh[fbase + h]) + __bfloat162float(cfl[fbase + h]);
    out[(size_t)b * cSD + h] = f * score;
  }
}

extern "C" void kernel_launch(void* const* d_in, const int* in_sizes, int n_in,
                              void* d_out, int out_size, void* d_ws, size_t ws_size,
                              hipStream_t stream) {
  const int* word = (const int*)d_in[0];
  const float* WE = (const float*)d_in[1];
  const float* preterm = (const float*)d_in[2];
  const float* G = (const float*)d_in[3];
  const float* starts = (const float*)d_in[4];
  const float* Wp = (const float*)d_in[5];
  const float* bp = (const float*)d_in[6];
  const float* Wm = (const float*)d_in[7];
  const float* bm = (const float*)d_in[8];
  float* out = (float*)d_out;
  float* ws = (float*)d_ws;

  size_t off = 0;
  float* chart_p = ws + off; off += (size_t)TRIC * cS;           // 17.3 MB
  float* chart_v = ws + off; off += (size_t)TRIC * cS;           // 17.3 MB
  __hip_bfloat16* cfh = (__hip_bfloat16*)(ws + off); off += (size_t)TRIC * cSD / 2; // 34.6 MB
  __hip_bfloat16* cfl = (__hip_bfloat16*)(ws + off); off += (size_t)TRIC * cSD / 2; // 34.6 MB
  float* Gll = ws + off; off += (size_t)cKQ * cNT;               // 1 MB
  float* Ghh = ws + off; off += (size_t)cKQ * cNT;               // 1 MB
  float* GsumT = ws + off; off += cS * cS;
  float* e_arr = ws + off; off += (size_t)2048 * 4096;           // 33.5 MB
  float* f_arr = ws + off; off += (size_t)2048 * 4096;           // 33.5 MB
  __hip_bfloat16* WmTh = (__hip_bfloat16*)(ws + off); off += (size_t)cSD * 1024 / 2;
  __hip_bfloat16* WmTl = (__hip_bfloat16*)(ws + off); off += (size_t)cSD * 1024 / 2;
  float* uv = ws + off; off += (size_t)TRIC * 1024;              // 138.4 MB packed
  float* Obuf0 = ws + off; off += (size_t)CHpad * cKQ;           // 32.5 MB
  float* Obuf1 = ws + off; off += (size_t)CHpad * cKQ;           // 32.5 MB
  float* scoresP = ws + off; off += (size_t)CHpad * KS * cNT;    // 8.1 MB
  // total 386.7 MB <= 409.6 MB (measured via harness fill WRITE_SIZE)

  auto hdB = [](int d) { return (long)cB * ((long)d * cL - (long)d * (d - 1) / 2); };

  k_prep_g<<<(cS * cS) / 256, 256, 0, stream>>>(G, Gll, Ghh, GsumT);
  k_prep_wmt<<<(1024 * 512) / 256, 256, 0, stream>>>(Wm, WmTh, WmTl);
  k_diag<<<cB * cL, 128, 0, stream>>>(word, preterm, GsumT, chart_p, chart_v);
  k_prep_e<<<dim3(2048 / 64, 4096 / 64), 256, 0, stream>>>(chart_p, G, e_arr);
  k_prep_f<<<dim3(2048 / 8, 4), 256, 0, stream>>>(chart_p, G, f_arr);
  k_feat0<<<dim3((cB * cL) / 64, cSD / 64), 256, 0, stream>>>(word, WE, Wp, bp, cfh, cfl);

  // Prologue P: uv(diag 0, M=2048) || outer(ln=2, hi-quadrant, d=0) -> Obuf0
  k_X<<<128 + 1984, 256, 0, stream>>>(nullptr, nullptr, scoresP, 0, 0, 0,
                                      cfh, cfl, WmTh, WmTl, uv, 0L, 2048, 128,
                                      chart_p, Obuf0, 2, 31, 0, 0, 64, 64);

  for (int ln = 2; ln <= cL; ++ln) {
    int n = cL - ln + 1, Bn = cB * n;
    int useGemm = (ln == 2 || ln >= 4) ? 1 : 0;
    int useEF = (ln >= 3) ? 1 : 0;
    // X(ln): scores(ln) || uv(diag ln-2, ln>=3) || outer(ln+1, 3<=ln<=31)
    int gx = useGemm ? (Bn + 127) / 128 : 0;
    int sB = gx * KS;
    int Mu = (ln >= 3) ? cB * (cL - (ln - 2)) : 0;
    int uB = (ln >= 3) ? ((Mu + 127) / 128) * 8 : 0;
    int oR = (ln >= 3 && ln <= cL - 1) ? cB * (cL - ln) : 0; // rows of diagonal ln+1
    if (sB + uB + oR > 0) {
      const float* Oin = (ln & 1) ? Obuf1 : Obuf0;
      float* Oout = ((ln + 1) & 1) ? Obuf1 : Obuf0;
      k_X<<<sB + uB + oR, 256, 0, stream>>>(
          Oin, (ln == 2) ? Ghh : Gll, scoresP, gx, Bn, sB,
          cfh, cfl, WmTh, WmTl, uv, hdB(ln - 2), Mu, uB,
          chart_p, Oout, ln + 1, cL - ln, 1, ln - 2, 0, 0);
    }
    // Y(ln): normp || combine
    k_Y<<<2 * Bn, 256, 0, stream>>>(scoresP, e_arr, f_arr, GsumT, chart_p, chart_v,
                                    uv, bm, cfh, cfl, ln, n, useGemm, useEF, Bn);
  }

  k_root<<<cB, 128, 0, stream>>>(chart_p, cfh, cfl, starts, out);
}